// Round 6
// baseline (756.566 us; speedup 1.0000x reference)
//
#include <hip/hip_runtime.h>
#include <math.h>

// GraphConv x5 (DGL norm='both') on MI355X.
// xp-layer invariant: each layer's epilogue writes xp = dout_is * lrelu(y),
// i.e. the *prescaled* input of the next layer. Middle layers are fully
// fused: gather(xp)->LDS tile -> GEMM(W)+b+lrelu+prescale -> xp_next.
// CSR built with ONE atomic pass: rank[e] = atomicAdd(din_cnt[dst])'s old
// value gives each edge its slot; scatter pass is atomic-free.
// R6: per-node edge lists sorted by src (wave64 bitonic). All concurrent
// waves then sweep src-space monotonically -> the live gather window
// shrinks to a few MB -> higher per-XCD L2 hit rate -> fewer L2 misses
// (the 2.2 TB/s miss path is the measured wall).

#define LRELU_SLOPE 0.01f
#define XPAD 129  // 128+1: LDS bank (lane+k)%32 -> 2-way on wave64 = free

// ---------------- preprocessing ----------------

__global__ void k_degcount_rank(const int* __restrict__ src, const int* __restrict__ dst,
                                int E, unsigned* __restrict__ dout_cnt,
                                unsigned* __restrict__ din_cnt, unsigned* __restrict__ rank) {
    int e = blockIdx.x * blockDim.x + threadIdx.x;
    if (e < E) {
        atomicAdd(&dout_cnt[src[e]], 1u);
        rank[e] = atomicAdd(&din_cnt[dst[e]], 1u);
    }
}

__global__ void k_invsqrt2(const unsigned* __restrict__ c0, float* __restrict__ i0,
                           const unsigned* __restrict__ c1, float* __restrict__ i1, int n) {
    int i = blockIdx.x * blockDim.x + threadIdx.x;
    if (i < n) {
        i0[i] = 1.0f / sqrtf(fmaxf((float)c0[i], 1.0f));
        i1[i] = 1.0f / sqrtf(fmaxf((float)c1[i], 1.0f));
    }
}

// blocked Hillis-Steele inclusive scan, 256/block
__global__ void k_scan_block(const unsigned* __restrict__ in, unsigned* __restrict__ out,
                             unsigned* __restrict__ bsum, int n) {
    __shared__ unsigned s[256];
    int g = blockIdx.x * 256 + threadIdx.x;
    unsigned v = (g < n) ? in[g] : 0u;
    s[threadIdx.x] = v;
    __syncthreads();
    for (int off = 1; off < 256; off <<= 1) {
        unsigned t = (threadIdx.x >= (unsigned)off) ? s[threadIdx.x - off] : 0u;
        __syncthreads();
        s[threadIdx.x] += t;
        __syncthreads();
    }
    if (g < n) out[g] = s[threadIdx.x];
    if (threadIdx.x == 255) bsum[blockIdx.x] = s[255];
}

__global__ void k_scan_single(unsigned* __restrict__ bsum, int n) {
    __shared__ unsigned s[1024];
    int t = threadIdx.x;
    s[t] = (t < n) ? bsum[t] : 0u;
    __syncthreads();
    for (int off = 1; off < 1024; off <<= 1) {
        unsigned v = (t >= off) ? s[t - off] : 0u;
        __syncthreads();
        s[t] += v;
        __syncthreads();
    }
    if (t < n) bsum[t] = (t == 0) ? 0u : s[t - 1];
}

__global__ void k_finalize_rowptr(const unsigned* __restrict__ scanned, const unsigned* __restrict__ boff,
                                  unsigned* __restrict__ row_ptr, int n) {
    int g = blockIdx.x * blockDim.x + threadIdx.x;
    if (g < n) row_ptr[g + 1] = scanned[g] + boff[g >> 8];
    if (g == 0) row_ptr[0] = 0u;
}

// atomic-free CSR fill using precomputed per-edge rank
__global__ void k_csr_scatter(const int* __restrict__ src, const int* __restrict__ dst, int E,
                              const unsigned* __restrict__ row_ptr, const unsigned* __restrict__ rank,
                              int* __restrict__ csr) {
    int e = blockIdx.x * blockDim.x + threadIdx.x;
    if (e < E) csr[row_ptr[dst[e]] + rank[e]] = src[e];
}

// sort each node's edge segment by src (perf-only: changes FP sum order
// within tolerance). One wave64 per node, in-register bitonic via shfl_xor.
// deg > 64 nodes are left unsorted (correct either way).
__global__ __launch_bounds__(512) void k_sortseg(int* __restrict__ csr,
                                                 const unsigned* __restrict__ row_ptr, int n) {
    int node = blockIdx.x * 8 + (threadIdx.x >> 6);
    if (node >= n) return;                 // wave-uniform
    int lane = threadIdx.x & 63;
    unsigned beg = row_ptr[node], end = row_ptr[node + 1];
    int deg = (int)(end - beg);
    if (deg <= 1 || deg > 64) return;      // wave-uniform
    int v = (lane < deg) ? csr[beg + lane] : 0x7fffffff;
#pragma unroll
    for (int k = 2; k <= 64; k <<= 1) {
#pragma unroll
        for (int j = k >> 1; j >= 1; j >>= 1) {
            int other = __shfl_xor(v, j, 64);
            bool up = ((lane & k) == 0);
            bool lower = ((lane & j) == 0);
            int mn = min(v, other), mx = max(v, other);
            v = (up == lower) ? mn : mx;
        }
    }
    if (lane < deg) csr[beg + lane] = v;
}

// ---------------- layer 1 (aggregate-first, 4-wide) ----------------

__global__ void k_prescale4(const float* __restrict__ x, const float* __restrict__ dout_is,
                            float* __restrict__ pf4, int n) {
    int i = blockIdx.x * blockDim.x + threadIdx.x;
    if (i >= n) return;
    float s = dout_is[i];
    float4 v = *reinterpret_cast<const float4*>(x + (size_t)i * 4);
    float4 o = {v.x * s, v.y * s, v.z * s, v.w * s};
    *reinterpret_cast<float4*>(pf4 + (size_t)i * 4) = o;
}

__global__ void k_gather4(const float* __restrict__ pf4, const int* __restrict__ csr,
                          const unsigned* __restrict__ row_ptr, const float* __restrict__ din_is,
                          float* __restrict__ g, int n) {
    int i = blockIdx.x * blockDim.x + threadIdx.x;
    if (i >= n) return;
    unsigned beg = row_ptr[i], end = row_ptr[i + 1];
    float4 acc = {0.f, 0.f, 0.f, 0.f};
    unsigned e = beg;
    for (; e + 4 <= end; e += 4) {
        int s0 = csr[e], s1 = csr[e + 1], s2 = csr[e + 2], s3 = csr[e + 3];
        float4 v0 = *reinterpret_cast<const float4*>(pf4 + (size_t)s0 * 4);
        float4 v1 = *reinterpret_cast<const float4*>(pf4 + (size_t)s1 * 4);
        float4 v2 = *reinterpret_cast<const float4*>(pf4 + (size_t)s2 * 4);
        float4 v3 = *reinterpret_cast<const float4*>(pf4 + (size_t)s3 * 4);
        acc.x += (v0.x + v1.x) + (v2.x + v3.x);
        acc.y += (v0.y + v1.y) + (v2.y + v3.y);
        acc.z += (v0.z + v1.z) + (v2.z + v3.z);
        acc.w += (v0.w + v1.w) + (v2.w + v3.w);
    }
    for (; e < end; ++e) {
        int s = csr[e];
        float4 v = *reinterpret_cast<const float4*>(pf4 + (size_t)s * 4);
        acc.x += v.x; acc.y += v.y; acc.z += v.z; acc.w += v.w;
    }
    float di = din_is[i];
    float4 o = {acc.x * di, acc.y * di, acc.z * di, acc.w * di};
    *reinterpret_cast<float4*>(g + (size_t)i * 4) = o;
}

// xp1[i][j] = dout_is[i] * lrelu(g[i] . W1[:,j] + b1[j])
__global__ void k_lin1b(const float* __restrict__ g, const float* __restrict__ W,
                        const float* __restrict__ b, const float* __restrict__ dout_is,
                        float* __restrict__ xp, int n) {
    int t = blockIdx.x * blockDim.x + threadIdx.x;
    int i = t >> 7, j = t & 127;
    if (i >= n) return;
    float4 gv = *reinterpret_cast<const float4*>(g + (size_t)i * 4);
    float acc = gv.x * W[0 * 128 + j] + gv.y * W[1 * 128 + j] + gv.z * W[2 * 128 + j] + gv.w * W[3 * 128 + j];
    float v = acc + b[j];
    v = (v >= 0.f) ? v : LRELU_SLOPE * v;
    xp[(size_t)i * 128 + j] = v * dout_is[i];
}

// ---------------- fused middle layer ----------------

// Per 64-node tile: phase 1 gathers g = din_is * sum_in(xp) into LDS;
// phase 2 GEMM with W (wave-uniform scalar loads), epilogue
// xo = dout_is * lrelu(g@W + b)  (= next layer's prescaled input).
__global__ __launch_bounds__(512) void k_gl128(const float* __restrict__ xp, const int* __restrict__ csr,
                                               const unsigned* __restrict__ row_ptr,
                                               const float* __restrict__ din_is, const float* __restrict__ dout_is,
                                               const float* __restrict__ W, const float* __restrict__ b,
                                               float* __restrict__ xo, int n) {
    __shared__ float xs[64 * XPAD];  // 33 KB
    const int t = threadIdx.x;
    const int bbase = blockIdx.x * 64;
    const int wave = t >> 6;
    const int lane = t & 63;
    const int half = lane >> 5;
    const int j4 = (lane & 31) * 4;

    // phase 1: gather. wave w, half h -> rows 2w+h (+16 per sweep).
    // 8-edge unroll, dual accumulators.
#pragma unroll
    for (int sweep = 0; sweep < 4; ++sweep) {
        int r = wave * 2 + half + sweep * 16;
        int node = bbase + r;
        float4 accA = {0.f, 0.f, 0.f, 0.f};
        float4 accB = {0.f, 0.f, 0.f, 0.f};
        if (node < n) {
            unsigned beg = row_ptr[node], end = row_ptr[node + 1];
            unsigned e = beg;
            for (; e + 8 <= end; e += 8) {
                int s0 = csr[e + 0], s1 = csr[e + 1], s2 = csr[e + 2], s3 = csr[e + 3];
                int s4 = csr[e + 4], s5 = csr[e + 5], s6 = csr[e + 6], s7 = csr[e + 7];
                float4 v0 = *reinterpret_cast<const float4*>(xp + (size_t)s0 * 128 + j4);
                float4 v1 = *reinterpret_cast<const float4*>(xp + (size_t)s1 * 128 + j4);
                float4 v2 = *reinterpret_cast<const float4*>(xp + (size_t)s2 * 128 + j4);
                float4 v3 = *reinterpret_cast<const float4*>(xp + (size_t)s3 * 128 + j4);
                float4 v4 = *reinterpret_cast<const float4*>(xp + (size_t)s4 * 128 + j4);
                float4 v5 = *reinterpret_cast<const float4*>(xp + (size_t)s5 * 128 + j4);
                float4 v6 = *reinterpret_cast<const float4*>(xp + (size_t)s6 * 128 + j4);
                float4 v7 = *reinterpret_cast<const float4*>(xp + (size_t)s7 * 128 + j4);
                accA.x += (v0.x + v1.x) + (v2.x + v3.x);
                accA.y += (v0.y + v1.y) + (v2.y + v3.y);
                accA.z += (v0.z + v1.z) + (v2.z + v3.z);
                accA.w += (v0.w + v1.w) + (v2.w + v3.w);
                accB.x += (v4.x + v5.x) + (v6.x + v7.x);
                accB.y += (v4.y + v5.y) + (v6.y + v7.y);
                accB.z += (v4.z + v5.z) + (v6.z + v7.z);
                accB.w += (v4.w + v5.w) + (v6.w + v7.w);
            }
            if (e + 4 <= end) {
                int s0 = csr[e + 0], s1 = csr[e + 1], s2 = csr[e + 2], s3 = csr[e + 3];
                float4 v0 = *reinterpret_cast<const float4*>(xp + (size_t)s0 * 128 + j4);
                float4 v1 = *reinterpret_cast<const float4*>(xp + (size_t)s1 * 128 + j4);
                float4 v2 = *reinterpret_cast<const float4*>(xp + (size_t)s2 * 128 + j4);
                float4 v3 = *reinterpret_cast<const float4*>(xp + (size_t)s3 * 128 + j4);
                accA.x += (v0.x + v1.x) + (v2.x + v3.x);
                accA.y += (v0.y + v1.y) + (v2.y + v3.y);
                accA.z += (v0.z + v1.z) + (v2.z + v3.z);
                accA.w += (v0.w + v1.w) + (v2.w + v3.w);
                e += 4;
            }
            for (; e < end; ++e) {
                int s = csr[e];
                float4 v = *reinterpret_cast<const float4*>(xp + (size_t)s * 128 + j4);
                accB.x += v.x; accB.y += v.y; accB.z += v.z; accB.w += v.w;
            }
            float di = din_is[node];
            accA.x = (accA.x + accB.x) * di;
            accA.y = (accA.y + accB.y) * di;
            accA.z = (accA.z + accB.z) * di;
            accA.w = (accA.w + accB.w) * di;
        }
        float* d = xs + r * XPAD + j4;
        d[0] = accA.x; d[1] = accA.y; d[2] = accA.z; d[3] = accA.w;
    }
    __syncthreads();

    // phase 2: GEMM. lane = node, wave = 16-wide j tile.
    const int jg = __builtin_amdgcn_readfirstlane(wave) & 7;
    const int j0 = jg * 16;
    const float* Wj = W + j0;
    const float* xrow = xs + lane * XPAD;

    float acc[16];
#pragma unroll
    for (int q = 0; q < 16; ++q) acc[q] = 0.f;

#pragma unroll 2
    for (int k = 0; k < 128; k += 4) {
        float x0 = xrow[k + 0];
        float x1 = xrow[k + 1];
        float x2 = xrow[k + 2];
        float x3 = xrow[k + 3];
        const float* w0 = Wj + (size_t)k * 128;
#pragma unroll
        for (int q = 0; q < 16; ++q) {
            acc[q] += x0 * w0[q] + x1 * w0[128 + q] + x2 * w0[256 + q] + x3 * w0[384 + q];
        }
    }

    int node = bbase + lane;
    if (node < n) {
        float s = dout_is[node];
        float* out = xo + (size_t)node * 128 + j0;
#pragma unroll
        for (int q = 0; q < 16; q += 4) {
            float v0 = acc[q + 0] + b[j0 + q + 0];
            float v1 = acc[q + 1] + b[j0 + q + 1];
            float v2 = acc[q + 2] + b[j0 + q + 2];
            float v3 = acc[q + 3] + b[j0 + q + 3];
            v0 = (v0 >= 0.f) ? v0 : LRELU_SLOPE * v0;
            v1 = (v1 >= 0.f) ? v1 : LRELU_SLOPE * v1;
            v2 = (v2 >= 0.f) ? v2 : LRELU_SLOPE * v2;
            v3 = (v3 >= 0.f) ? v3 : LRELU_SLOPE * v3;
            float4 o = {v0 * s, v1 * s, v2 * s, v3 * s};
            *reinterpret_cast<float4*>(out + q) = o;
        }
    }
}

// ---------------- layer 5 ----------------

// input xp is already prescaled by dout_is
__global__ __launch_bounds__(256) void k_lin5v(const float* __restrict__ xp, const float* __restrict__ W,
                                               float* __restrict__ h, int n) {
    int node = blockIdx.x * 8 + (threadIdx.x >> 5);
    if (node >= n) return;
    int l = threadIdx.x & 31;
    int k4 = l * 4;
    float4 xv = *reinterpret_cast<const float4*>(xp + (size_t)node * 128 + k4);
    float4 wA = *reinterpret_cast<const float4*>(W + (size_t)k4 * 3);
    float4 wB = *reinterpret_cast<const float4*>(W + (size_t)k4 * 3 + 4);
    float4 wC = *reinterpret_cast<const float4*>(W + (size_t)k4 * 3 + 8);
    float p0 = xv.x * wA.x + xv.y * wA.w + xv.z * wB.z + xv.w * wC.y;
    float p1 = xv.x * wA.y + xv.y * wB.x + xv.z * wB.w + xv.w * wC.z;
    float p2 = xv.x * wA.z + xv.y * wB.y + xv.z * wC.x + xv.w * wC.w;
    for (int off = 16; off; off >>= 1) {
        p0 += __shfl_xor(p0, off, 32);
        p1 += __shfl_xor(p1, off, 32);
        p2 += __shfl_xor(p2, off, 32);
    }
    if (l == 0) {
        h[(size_t)node * 3 + 0] = p0;
        h[(size_t)node * 3 + 1] = p1;
        h[(size_t)node * 3 + 2] = p2;
    }
}

__global__ void k_gather3(const float* __restrict__ h, const int* __restrict__ csr,
                          const unsigned* __restrict__ row_ptr, const float* __restrict__ din_is,
                          const float* __restrict__ b, float* __restrict__ out, int n) {
    int i = blockIdx.x * blockDim.x + threadIdx.x;
    if (i >= n) return;
    unsigned beg = row_ptr[i], end = row_ptr[i + 1];
    float a0 = 0.f, a1 = 0.f, a2 = 0.f;
    for (unsigned e = beg; e < end; ++e) {
        int s = csr[e];
        a0 += h[(size_t)s * 3 + 0];
        a1 += h[(size_t)s * 3 + 1];
        a2 += h[(size_t)s * 3 + 2];
    }
    float di = din_is[i];
    out[(size_t)i * 3 + 0] = a0 * di + b[0];
    out[(size_t)i * 3 + 1] = a1 * di + b[1];
    out[(size_t)i * 3 + 2] = a2 * di + b[2];
}

// ---------------- launch ----------------

extern "C" void kernel_launch(void* const* d_in, const int* in_sizes, int n_in,
                              void* d_out, int out_size, void* d_ws, size_t ws_size,
                              hipStream_t stream) {
    const float* features = (const float*)d_in[0];
    const int* esrc = (const int*)d_in[1];
    const int* edst = (const int*)d_in[2];
    const float* W1 = (const float*)d_in[3];  const float* b1 = (const float*)d_in[4];
    const float* W2 = (const float*)d_in[5];  const float* b2 = (const float*)d_in[6];
    const float* W3 = (const float*)d_in[7];  const float* b3 = (const float*)d_in[8];
    const float* W4 = (const float*)d_in[9];  const float* b4 = (const float*)d_in[10];
    const float* W5 = (const float*)d_in[11]; const float* b5 = (const float*)d_in[12];

    const int N = in_sizes[0] / 4;
    const int E = in_sizes[1];

    size_t off = 0;
    auto carve = [&](size_t bytes) -> void* {
        void* p = (char*)d_ws + off;
        off = (off + bytes + 255) & ~(size_t)255;
        return p;
    };
    float*    A        = (float*)carve((size_t)N * 128 * 4);
    float*    B        = (float*)carve((size_t)N * 128 * 4);
    int*      csr      = (int*)carve((size_t)E * 4);
    unsigned* row_ptr  = (unsigned*)carve((size_t)(N + 1) * 4);
    unsigned* dout_cnt = (unsigned*)carve((size_t)N * 4);
    unsigned* din_cnt  = (unsigned*)carve((size_t)N * 4);
    float*    dout_is  = (float*)carve((size_t)N * 4);
    float*    din_is   = (float*)carve((size_t)N * 4);
    unsigned* scan_tmp = (unsigned*)carve((size_t)N * 4);
    unsigned* bsum     = (unsigned*)carve(4096);
    float*    h5       = (float*)carve((size_t)N * 3 * 4);
    (void)ws_size;
    // aliases: rank lives in A (consumed by csr_scatter before A's first
    // real use); pf4/g4 live in B (consumed by lin1b before B's first use)
    unsigned* rank = (unsigned*)A;
    float* pf4 = B;
    float* g4  = B + (size_t)N * 4;

    hipMemsetAsync(dout_cnt, 0, (size_t)N * 4, stream);
    hipMemsetAsync(din_cnt, 0, (size_t)N * 4, stream);

    k_degcount_rank<<<(E + 255) / 256, 256, 0, stream>>>(esrc, edst, E, dout_cnt, din_cnt, rank);
    k_invsqrt2<<<(N + 255) / 256, 256, 0, stream>>>(dout_cnt, dout_is, din_cnt, din_is, N);

    int nscan = (N + 255) / 256;
    k_scan_block<<<nscan, 256, 0, stream>>>(din_cnt, scan_tmp, bsum, N);
    k_scan_single<<<1, 1024, 0, stream>>>(bsum, nscan);
    k_finalize_rowptr<<<(N + 255) / 256, 256, 0, stream>>>(scan_tmp, bsum, row_ptr, N);
    k_csr_scatter<<<(E + 255) / 256, 256, 0, stream>>>(esrc, edst, E, row_ptr, rank, csr);
    k_sortseg<<<(N + 7) / 8, 512, 0, stream>>>(csr, row_ptr, N);

    // layer 1: aggregate 4-wide first, then 4->128 GEMM (+b+lrelu+prescale)
    k_prescale4<<<(N + 255) / 256, 256, 0, stream>>>(features, dout_is, pf4, N);
    k_gather4<<<(N + 255) / 256, 256, 0, stream>>>(pf4, csr, row_ptr, din_is, g4, N);
    k_lin1b<<<((size_t)N * 128 + 255) / 256, 256, 0, stream>>>(g4, W1, b1, dout_is, A, N);

    // layers 2-4 fused: gather + GEMM + epilogue
    int glGrid = (N + 63) / 64;
    k_gl128<<<glGrid, 512, 0, stream>>>(A, csr, row_ptr, din_is, dout_is, W2, b2, B, N);
    k_gl128<<<glGrid, 512, 0, stream>>>(B, csr, row_ptr, din_is, dout_is, W3, b3, A, N);
    k_gl128<<<glGrid, 512, 0, stream>>>(A, csr, row_ptr, din_is, dout_is, W4, b4, B, N);

    // layer 5: 128 -> 3 (input already prescaled), then 3-wide gather
    k_lin5v<<<(N + 7) / 8, 256, 0, stream>>>(B, W5, h5, N);
    k_gather3<<<(N + 255) / 256, 256, 0, stream>>>(h5, csr, row_ptr, din_is, b5, (float*)d_out, N);
}

// Round 7
// 634.439 us; speedup vs baseline: 1.1925x; 1.1925x over previous
//
#include <hip/hip_runtime.h>
#include <math.h>

// GraphConv x5 (DGL norm='both') on MI355X.
// xp-layer invariant: each layer's epilogue writes xp = dout_is * lrelu(y).
// Middle layers fused: gather(xp)->LDS -> GEMM(W)+b+lrelu+prescale -> xp.
// R7: preprocessing rewritten as LDS-binned two-pass bucket partition
// (391 buckets of 256 nodes). Replaces 3.2M device-scope atomics
// (degcount_rank ~130us + csr_scatter) with ~200K global atomics + LDS
// histograms/scans. gl128 is at its compulsory L2-miss floor (377MB ~
// 354MB analytic floor) and is left untouched.

#define LRELU_SLOPE 0.01f
#define XPAD 129     // 128+1: LDS bank (lane+k)%32 -> 2-way on wave64 = free
#define MAXBUCK 512  // supports N <= 131072

// ---------------- bucket-partition preprocessing ----------------

__device__ inline void chunk_range(int E, int nchunks, int cid, int& lo, int& hi) {
    int chunk = (E + nchunks - 1) / nchunks;
    lo = cid * chunk;
    hi = min(E, lo + chunk);
}

// per-block LDS histogram of key>>8; reserve disjoint per-block ranges
__global__ __launch_bounds__(256) void k_part_hist(const int* __restrict__ key, int E, int nbuck,
                                                   unsigned* __restrict__ gHist,
                                                   unsigned* __restrict__ blockBase) {
    __shared__ unsigned h[MAXBUCK];
    for (int i = threadIdx.x; i < nbuck; i += 256) h[i] = 0u;
    __syncthreads();
    int lo, hi;
    chunk_range(E, gridDim.x, blockIdx.x, lo, hi);
    for (int e = lo + threadIdx.x; e < hi; e += 256)
        atomicAdd(&h[key[e] >> 8], 1u);
    __syncthreads();
    for (int i = threadIdx.x; i < nbuck; i += 256)
        blockBase[(size_t)blockIdx.x * nbuck + i] = atomicAdd(&gHist[i], h[i]);
}

// single-block scan: bucketStart[0..nbuck] from gHist; optionally row_ptr[N]=E
__global__ __launch_bounds__(512) void k_part_scan(const unsigned* __restrict__ gHist, int nbuck,
                                                   unsigned* __restrict__ bucketStart,
                                                   unsigned* __restrict__ row_ptr_last, unsigned Eval) {
    __shared__ unsigned s[MAXBUCK];
    int t = threadIdx.x;
    s[t] = (t < nbuck) ? gHist[t] : 0u;
    __syncthreads();
    for (int off = 1; off < MAXBUCK; off <<= 1) {
        unsigned v = (t >= off) ? s[t - off] : 0u;
        __syncthreads();
        s[t] += v;
        __syncthreads();
    }
    if (t <= nbuck) bucketStart[t] = (t == 0) ? 0u : s[t - 1];
    if (t == 0 && row_ptr_last) *row_ptr_last = Eval;
}

// scatter (src,dst) pairs into dst-buckets (disjoint per-block ranges)
__global__ __launch_bounds__(256) void k_part_scatter2(const int* __restrict__ src, const int* __restrict__ dst,
                                                       int E, int nbuck,
                                                       const unsigned* __restrict__ bucketStart,
                                                       const unsigned* __restrict__ blockBase,
                                                       int2* __restrict__ out) {
    __shared__ unsigned cur[MAXBUCK];
    for (int i = threadIdx.x; i < nbuck; i += 256)
        cur[i] = bucketStart[i] + blockBase[(size_t)blockIdx.x * nbuck + i];
    __syncthreads();
    int lo, hi;
    chunk_range(E, gridDim.x, blockIdx.x, lo, hi);
    for (int e = lo + threadIdx.x; e < hi; e += 256) {
        int s = src[e], d = dst[e];
        unsigned pos = atomicAdd(&cur[d >> 8], 1u);
        out[pos] = make_int2(s, d);
    }
}

// scatter src values into src-buckets (for dout counting)
__global__ __launch_bounds__(256) void k_part_scatter1(const int* __restrict__ src, int E, int nbuck,
                                                       const unsigned* __restrict__ bucketStart,
                                                       const unsigned* __restrict__ blockBase,
                                                       int* __restrict__ out) {
    __shared__ unsigned cur[MAXBUCK];
    for (int i = threadIdx.x; i < nbuck; i += 256)
        cur[i] = bucketStart[i] + blockBase[(size_t)blockIdx.x * nbuck + i];
    __syncthreads();
    int lo, hi;
    chunk_range(E, gridDim.x, blockIdx.x, lo, hi);
    for (int e = lo + threadIdx.x; e < hi; e += 256) {
        int s = src[e];
        unsigned pos = atomicAdd(&cur[s >> 8], 1u);
        out[pos] = s;
    }
}

// per-bucket (256 nodes): din counts, row_ptr, and csr fill — LDS atomics only
__global__ __launch_bounds__(256) void k_bucket_csr(const int2* __restrict__ pairs,
                                                    const unsigned* __restrict__ bucketStart,
                                                    unsigned* __restrict__ row_ptr,
                                                    unsigned* __restrict__ din_cnt,
                                                    int* __restrict__ csr, int n) {
    __shared__ unsigned hist[256];
    __shared__ unsigned scanw[256];
    __shared__ unsigned cur[256];
    int b = blockIdx.x, t = threadIdx.x;
    unsigned beg = bucketStart[b], end = bucketStart[b + 1];
    hist[t] = 0u;
    __syncthreads();
    for (unsigned e = beg + t; e < end; e += 256)
        atomicAdd(&hist[pairs[e].y & 255], 1u);
    __syncthreads();
    scanw[t] = hist[t];
    __syncthreads();
    for (int off = 1; off < 256; off <<= 1) {
        unsigned u = (t >= off) ? scanw[t - off] : 0u;
        __syncthreads();
        scanw[t] += u;
        __syncthreads();
    }
    unsigned excl = scanw[t] - hist[t];
    int node = (b << 8) + t;
    if (node < n) {
        row_ptr[node] = beg + excl;
        din_cnt[node] = hist[t];
    }
    cur[t] = excl;
    __syncthreads();
    for (unsigned e = beg + t; e < end; e += 256) {
        int2 p = pairs[e];
        unsigned pos = beg + atomicAdd(&cur[p.y & 255], 1u);
        csr[pos] = p.x;
    }
}

// per-bucket src-value histogram -> dout counts
__global__ __launch_bounds__(256) void k_bucket_cnt(const int* __restrict__ vals,
                                                    const unsigned* __restrict__ bucketStart,
                                                    unsigned* __restrict__ dout_cnt, int n) {
    __shared__ unsigned hist[256];
    int b = blockIdx.x, t = threadIdx.x;
    unsigned beg = bucketStart[b], end = bucketStart[b + 1];
    hist[t] = 0u;
    __syncthreads();
    for (unsigned e = beg + t; e < end; e += 256)
        atomicAdd(&hist[vals[e] & 255], 1u);
    __syncthreads();
    int node = (b << 8) + t;
    if (node < n) dout_cnt[node] = hist[t];
}

__global__ void k_invsqrt2(const unsigned* __restrict__ c0, float* __restrict__ i0,
                           const unsigned* __restrict__ c1, float* __restrict__ i1, int n) {
    int i = blockIdx.x * blockDim.x + threadIdx.x;
    if (i < n) {
        i0[i] = 1.0f / sqrtf(fmaxf((float)c0[i], 1.0f));
        i1[i] = 1.0f / sqrtf(fmaxf((float)c1[i], 1.0f));
    }
}

// ---------------- layer 1 (aggregate-first, 4-wide) ----------------

__global__ void k_prescale4(const float* __restrict__ x, const float* __restrict__ dout_is,
                            float* __restrict__ pf4, int n) {
    int i = blockIdx.x * blockDim.x + threadIdx.x;
    if (i >= n) return;
    float s = dout_is[i];
    float4 v = *reinterpret_cast<const float4*>(x + (size_t)i * 4);
    float4 o = {v.x * s, v.y * s, v.z * s, v.w * s};
    *reinterpret_cast<float4*>(pf4 + (size_t)i * 4) = o;
}

__global__ void k_gather4(const float* __restrict__ pf4, const int* __restrict__ csr,
                          const unsigned* __restrict__ row_ptr, const float* __restrict__ din_is,
                          float* __restrict__ g, int n) {
    int i = blockIdx.x * blockDim.x + threadIdx.x;
    if (i >= n) return;
    unsigned beg = row_ptr[i], end = row_ptr[i + 1];
    float4 acc = {0.f, 0.f, 0.f, 0.f};
    unsigned e = beg;
    for (; e + 4 <= end; e += 4) {
        int s0 = csr[e], s1 = csr[e + 1], s2 = csr[e + 2], s3 = csr[e + 3];
        float4 v0 = *reinterpret_cast<const float4*>(pf4 + (size_t)s0 * 4);
        float4 v1 = *reinterpret_cast<const float4*>(pf4 + (size_t)s1 * 4);
        float4 v2 = *reinterpret_cast<const float4*>(pf4 + (size_t)s2 * 4);
        float4 v3 = *reinterpret_cast<const float4*>(pf4 + (size_t)s3 * 4);
        acc.x += (v0.x + v1.x) + (v2.x + v3.x);
        acc.y += (v0.y + v1.y) + (v2.y + v3.y);
        acc.z += (v0.z + v1.z) + (v2.z + v3.z);
        acc.w += (v0.w + v1.w) + (v2.w + v3.w);
    }
    for (; e < end; ++e) {
        int s = csr[e];
        float4 v = *reinterpret_cast<const float4*>(pf4 + (size_t)s * 4);
        acc.x += v.x; acc.y += v.y; acc.z += v.z; acc.w += v.w;
    }
    float di = din_is[i];
    float4 o = {acc.x * di, acc.y * di, acc.z * di, acc.w * di};
    *reinterpret_cast<float4*>(g + (size_t)i * 4) = o;
}

// xp1[i][j] = dout_is[i] * lrelu(g[i] . W1[:,j] + b1[j])
__global__ void k_lin1b(const float* __restrict__ g, const float* __restrict__ W,
                        const float* __restrict__ b, const float* __restrict__ dout_is,
                        float* __restrict__ xp, int n) {
    int t = blockIdx.x * blockDim.x + threadIdx.x;
    int i = t >> 7, j = t & 127;
    if (i >= n) return;
    float4 gv = *reinterpret_cast<const float4*>(g + (size_t)i * 4);
    float acc = gv.x * W[0 * 128 + j] + gv.y * W[1 * 128 + j] + gv.z * W[2 * 128 + j] + gv.w * W[3 * 128 + j];
    float v = acc + b[j];
    v = (v >= 0.f) ? v : LRELU_SLOPE * v;
    xp[(size_t)i * 128 + j] = v * dout_is[i];
}

// ---------------- fused middle layer ----------------

__global__ __launch_bounds__(512) void k_gl128(const float* __restrict__ xp, const int* __restrict__ csr,
                                               const unsigned* __restrict__ row_ptr,
                                               const float* __restrict__ din_is, const float* __restrict__ dout_is,
                                               const float* __restrict__ W, const float* __restrict__ b,
                                               float* __restrict__ xo, int n) {
    __shared__ float xs[64 * XPAD];  // 33 KB
    const int t = threadIdx.x;
    const int bbase = blockIdx.x * 64;
    const int wave = t >> 6;
    const int lane = t & 63;
    const int half = lane >> 5;
    const int j4 = (lane & 31) * 4;

#pragma unroll
    for (int sweep = 0; sweep < 4; ++sweep) {
        int r = wave * 2 + half + sweep * 16;
        int node = bbase + r;
        float4 accA = {0.f, 0.f, 0.f, 0.f};
        float4 accB = {0.f, 0.f, 0.f, 0.f};
        if (node < n) {
            unsigned beg = row_ptr[node], end = row_ptr[node + 1];
            unsigned e = beg;
            for (; e + 8 <= end; e += 8) {
                int s0 = csr[e + 0], s1 = csr[e + 1], s2 = csr[e + 2], s3 = csr[e + 3];
                int s4 = csr[e + 4], s5 = csr[e + 5], s6 = csr[e + 6], s7 = csr[e + 7];
                float4 v0 = *reinterpret_cast<const float4*>(xp + (size_t)s0 * 128 + j4);
                float4 v1 = *reinterpret_cast<const float4*>(xp + (size_t)s1 * 128 + j4);
                float4 v2 = *reinterpret_cast<const float4*>(xp + (size_t)s2 * 128 + j4);
                float4 v3 = *reinterpret_cast<const float4*>(xp + (size_t)s3 * 128 + j4);
                float4 v4 = *reinterpret_cast<const float4*>(xp + (size_t)s4 * 128 + j4);
                float4 v5 = *reinterpret_cast<const float4*>(xp + (size_t)s5 * 128 + j4);
                float4 v6 = *reinterpret_cast<const float4*>(xp + (size_t)s6 * 128 + j4);
                float4 v7 = *reinterpret_cast<const float4*>(xp + (size_t)s7 * 128 + j4);
                accA.x += (v0.x + v1.x) + (v2.x + v3.x);
                accA.y += (v0.y + v1.y) + (v2.y + v3.y);
                accA.z += (v0.z + v1.z) + (v2.z + v3.z);
                accA.w += (v0.w + v1.w) + (v2.w + v3.w);
                accB.x += (v4.x + v5.x) + (v6.x + v7.x);
                accB.y += (v4.y + v5.y) + (v6.y + v7.y);
                accB.z += (v4.z + v5.z) + (v6.z + v7.z);
                accB.w += (v4.w + v5.w) + (v6.w + v7.w);
            }
            if (e + 4 <= end) {
                int s0 = csr[e + 0], s1 = csr[e + 1], s2 = csr[e + 2], s3 = csr[e + 3];
                float4 v0 = *reinterpret_cast<const float4*>(xp + (size_t)s0 * 128 + j4);
                float4 v1 = *reinterpret_cast<const float4*>(xp + (size_t)s1 * 128 + j4);
                float4 v2 = *reinterpret_cast<const float4*>(xp + (size_t)s2 * 128 + j4);
                float4 v3 = *reinterpret_cast<const float4*>(xp + (size_t)s3 * 128 + j4);
                accA.x += (v0.x + v1.x) + (v2.x + v3.x);
                accA.y += (v0.y + v1.y) + (v2.y + v3.y);
                accA.z += (v0.z + v1.z) + (v2.z + v3.z);
                accA.w += (v0.w + v1.w) + (v2.w + v3.w);
                e += 4;
            }
            for (; e < end; ++e) {
                int s = csr[e];
                float4 v = *reinterpret_cast<const float4*>(xp + (size_t)s * 128 + j4);
                accB.x += v.x; accB.y += v.y; accB.z += v.z; accB.w += v.w;
            }
            float di = din_is[node];
            accA.x = (accA.x + accB.x) * di;
            accA.y = (accA.y + accB.y) * di;
            accA.z = (accA.z + accB.z) * di;
            accA.w = (accA.w + accB.w) * di;
        }
        float* d = xs + r * XPAD + j4;
        d[0] = accA.x; d[1] = accA.y; d[2] = accA.z; d[3] = accA.w;
    }
    __syncthreads();

    const int jg = __builtin_amdgcn_readfirstlane(wave) & 7;
    const int j0 = jg * 16;
    const float* Wj = W + j0;
    const float* xrow = xs + lane * XPAD;

    float acc[16];
#pragma unroll
    for (int q = 0; q < 16; ++q) acc[q] = 0.f;

#pragma unroll 2
    for (int k = 0; k < 128; k += 4) {
        float x0 = xrow[k + 0];
        float x1 = xrow[k + 1];
        float x2 = xrow[k + 2];
        float x3 = xrow[k + 3];
        const float* w0 = Wj + (size_t)k * 128;
#pragma unroll
        for (int q = 0; q < 16; ++q) {
            acc[q] += x0 * w0[q] + x1 * w0[128 + q] + x2 * w0[256 + q] + x3 * w0[384 + q];
        }
    }

    int node = bbase + lane;
    if (node < n) {
        float s = dout_is[node];
        float* out = xo + (size_t)node * 128 + j0;
#pragma unroll
        for (int q = 0; q < 16; q += 4) {
            float v0 = acc[q + 0] + b[j0 + q + 0];
            float v1 = acc[q + 1] + b[j0 + q + 1];
            float v2 = acc[q + 2] + b[j0 + q + 2];
            float v3 = acc[q + 3] + b[j0 + q + 3];
            v0 = (v0 >= 0.f) ? v0 : LRELU_SLOPE * v0;
            v1 = (v1 >= 0.f) ? v1 : LRELU_SLOPE * v1;
            v2 = (v2 >= 0.f) ? v2 : LRELU_SLOPE * v2;
            v3 = (v3 >= 0.f) ? v3 : LRELU_SLOPE * v3;
            float4 o = {v0 * s, v1 * s, v2 * s, v3 * s};
            *reinterpret_cast<float4*>(out + q) = o;
        }
    }
}

// ---------------- layer 5 ----------------

__global__ __launch_bounds__(256) void k_lin5v(const float* __restrict__ xp, const float* __restrict__ W,
                                               float* __restrict__ h, int n) {
    int node = blockIdx.x * 8 + (threadIdx.x >> 5);
    if (node >= n) return;
    int l = threadIdx.x & 31;
    int k4 = l * 4;
    float4 xv = *reinterpret_cast<const float4*>(xp + (size_t)node * 128 + k4);
    float4 wA = *reinterpret_cast<const float4*>(W + (size_t)k4 * 3);
    float4 wB = *reinterpret_cast<const float4*>(W + (size_t)k4 * 3 + 4);
    float4 wC = *reinterpret_cast<const float4*>(W + (size_t)k4 * 3 + 8);
    float p0 = xv.x * wA.x + xv.y * wA.w + xv.z * wB.z + xv.w * wC.y;
    float p1 = xv.x * wA.y + xv.y * wB.x + xv.z * wB.w + xv.w * wC.z;
    float p2 = xv.x * wA.z + xv.y * wB.y + xv.z * wC.x + xv.w * wC.w;
    for (int off = 16; off; off >>= 1) {
        p0 += __shfl_xor(p0, off, 32);
        p1 += __shfl_xor(p1, off, 32);
        p2 += __shfl_xor(p2, off, 32);
    }
    if (l == 0) {
        h[(size_t)node * 3 + 0] = p0;
        h[(size_t)node * 3 + 1] = p1;
        h[(size_t)node * 3 + 2] = p2;
    }
}

__global__ void k_gather3(const float* __restrict__ h, const int* __restrict__ csr,
                          const unsigned* __restrict__ row_ptr, const float* __restrict__ din_is,
                          const float* __restrict__ b, float* __restrict__ out, int n) {
    int i = blockIdx.x * blockDim.x + threadIdx.x;
    if (i >= n) return;
    unsigned beg = row_ptr[i], end = row_ptr[i + 1];
    float a0 = 0.f, a1 = 0.f, a2 = 0.f;
    for (unsigned e = beg; e < end; ++e) {
        int s = csr[e];
        a0 += h[(size_t)s * 3 + 0];
        a1 += h[(size_t)s * 3 + 1];
        a2 += h[(size_t)s * 3 + 2];
    }
    float di = din_is[i];
    out[(size_t)i * 3 + 0] = a0 * di + b[0];
    out[(size_t)i * 3 + 1] = a1 * di + b[1];
    out[(size_t)i * 3 + 2] = a2 * di + b[2];
}

// ---------------- launch ----------------

extern "C" void kernel_launch(void* const* d_in, const int* in_sizes, int n_in,
                              void* d_out, int out_size, void* d_ws, size_t ws_size,
                              hipStream_t stream) {
    const float* features = (const float*)d_in[0];
    const int* esrc = (const int*)d_in[1];
    const int* edst = (const int*)d_in[2];
    const float* W1 = (const float*)d_in[3];  const float* b1 = (const float*)d_in[4];
    const float* W2 = (const float*)d_in[5];  const float* b2 = (const float*)d_in[6];
    const float* W3 = (const float*)d_in[7];  const float* b3 = (const float*)d_in[8];
    const float* W4 = (const float*)d_in[9];  const float* b4 = (const float*)d_in[10];
    const float* W5 = (const float*)d_in[11]; const float* b5 = (const float*)d_in[12];

    const int N = in_sizes[0] / 4;
    const int E = in_sizes[1];
    const int nbuck = (N + 255) / 256;  // 391 for N=100K (<= MAXBUCK)
    const int NPB = 256;                // partition blocks

    size_t off = 0;
    auto carve = [&](size_t bytes) -> void* {
        void* p = (char*)d_ws + off;
        off = (off + bytes + 255) & ~(size_t)255;
        return p;
    };
    float*    A         = (float*)carve((size_t)N * 128 * 4);
    float*    B         = (float*)carve((size_t)N * 128 * 4);
    int*      csr       = (int*)carve((size_t)E * 4);
    unsigned* row_ptr   = (unsigned*)carve((size_t)(N + 1) * 4);
    unsigned* dout_cnt  = (unsigned*)carve((size_t)N * 4);
    unsigned* din_cnt   = (unsigned*)carve((size_t)N * 4);
    float*    dout_is   = (float*)carve((size_t)N * 4);
    float*    din_is    = (float*)carve((size_t)N * 4);
    unsigned* gHistD    = (unsigned*)carve((size_t)MAXBUCK * 4);
    unsigned* gHistS    = (unsigned*)carve((size_t)MAXBUCK * 4);
    unsigned* bstartD   = (unsigned*)carve((size_t)(MAXBUCK + 1) * 4);
    unsigned* bstartS   = (unsigned*)carve((size_t)(MAXBUCK + 1) * 4);
    unsigned* blockBaseD = (unsigned*)carve((size_t)NPB * nbuck * 4);
    unsigned* blockBaseS = (unsigned*)carve((size_t)NPB * nbuck * 4);
    float*    h5        = (float*)carve((size_t)N * 3 * 4);
    (void)ws_size;
    // aliases inside A (consumed before A's first real use by lin1b):
    int2* pairs  = (int2*)A;                       // E * 8 bytes
    int*  srcbuf = (int*)((char*)A + (size_t)E * 8); // E * 4 bytes
    // aliases inside B (consumed by lin1b before B written... B is written
    // by gl128 layer2 output AFTER these are dead):
    float* pf4 = B;
    float* g4  = B + (size_t)N * 4;

    hipMemsetAsync(gHistD, 0, (size_t)MAXBUCK * 4, stream);
    hipMemsetAsync(gHistS, 0, (size_t)MAXBUCK * 4, stream);

    // ---- bucket-partition preprocessing ----
    k_part_hist<<<NPB, 256, 0, stream>>>(edst, E, nbuck, gHistD, blockBaseD);
    k_part_hist<<<NPB, 256, 0, stream>>>(esrc, E, nbuck, gHistS, blockBaseS);
    k_part_scan<<<1, 512, 0, stream>>>(gHistD, nbuck, bstartD, row_ptr + N, (unsigned)E);
    k_part_scan<<<1, 512, 0, stream>>>(gHistS, nbuck, bstartS, (unsigned*)nullptr, 0u);
    k_part_scatter2<<<NPB, 256, 0, stream>>>(esrc, edst, E, nbuck, bstartD, blockBaseD, pairs);
    k_part_scatter1<<<NPB, 256, 0, stream>>>(esrc, E, nbuck, bstartS, blockBaseS, srcbuf);
    k_bucket_csr<<<nbuck, 256, 0, stream>>>(pairs, bstartD, row_ptr, din_cnt, csr, N);
    k_bucket_cnt<<<nbuck, 256, 0, stream>>>(srcbuf, bstartS, dout_cnt, N);
    k_invsqrt2<<<(N + 255) / 256, 256, 0, stream>>>(dout_cnt, dout_is, din_cnt, din_is, N);

    // ---- layer 1: aggregate 4-wide first, then 4->128 GEMM ----
    k_prescale4<<<(N + 255) / 256, 256, 0, stream>>>(features, dout_is, pf4, N);
    k_gather4<<<(N + 255) / 256, 256, 0, stream>>>(pf4, csr, row_ptr, din_is, g4, N);
    k_lin1b<<<((size_t)N * 128 + 255) / 256, 256, 0, stream>>>(g4, W1, b1, dout_is, A, N);

    // ---- layers 2-4 fused: gather + GEMM + epilogue ----
    int glGrid = (N + 63) / 64;
    k_gl128<<<glGrid, 512, 0, stream>>>(A, csr, row_ptr, din_is, dout_is, W2, b2, B, N);
    k_gl128<<<glGrid, 512, 0, stream>>>(B, csr, row_ptr, din_is, dout_is, W3, b3, A, N);
    k_gl128<<<glGrid, 512, 0, stream>>>(A, csr, row_ptr, din_is, dout_is, W4, b4, B, N);

    // ---- layer 5: 128 -> 3, then 3-wide gather ----
    k_lin5v<<<(N + 7) / 8, 256, 0, stream>>>(B, W5, h5, N);
    k_gather3<<<(N + 255) / 256, 256, 0, stream>>>(h5, csr, row_ptr, din_is, b5, (float*)d_out, N);
}

// Round 8
// 565.012 us; speedup vs baseline: 1.3390x; 1.1229x over previous
//
#include <hip/hip_runtime.h>
#include <math.h>

// GraphConv x5 (DGL norm='both') on MI355X.
// xp-layer invariant: epilogues write xp = dout_is * lrelu(y).
// R8: layer-2 gather reads 4-wide a4 (L2-resident, 1.6MB) and recomputes
// xp1 per edge in-register (W1 fragment per lane) — dodges the 377MB
// compulsory-miss floor that layers 3/4 (128-wide inputs) must pay.
// Identity used: d*lrelu(x) = lrelu(d*x) for d>0.

#define LRELU_SLOPE 0.01f
#define XPAD 129     // 128+1: LDS bank (lane+k)%32 -> 2-way on wave64 = free
#define MAXBUCK 512  // supports N <= 131072

// ---------------- bucket-partition preprocessing ----------------

__device__ inline void chunk_range(int E, int nchunks, int cid, int& lo, int& hi) {
    int chunk = (E + nchunks - 1) / nchunks;
    lo = cid * chunk;
    hi = min(E, lo + chunk);
}

// fused per-block LDS histograms of src>>8 and dst>>8
__global__ __launch_bounds__(256) void k_part_hist2(const int* __restrict__ src, const int* __restrict__ dst,
                                                    int E, int nbuck,
                                                    unsigned* __restrict__ gHistS, unsigned* __restrict__ gHistD,
                                                    unsigned* __restrict__ blockBaseS, unsigned* __restrict__ blockBaseD) {
    __shared__ unsigned hs[MAXBUCK];
    __shared__ unsigned hd[MAXBUCK];
    for (int i = threadIdx.x; i < nbuck; i += 256) { hs[i] = 0u; hd[i] = 0u; }
    __syncthreads();
    int lo, hi;
    chunk_range(E, gridDim.x, blockIdx.x, lo, hi);
    for (int e = lo + threadIdx.x; e < hi; e += 256) {
        atomicAdd(&hs[src[e] >> 8], 1u);
        atomicAdd(&hd[dst[e] >> 8], 1u);
    }
    __syncthreads();
    for (int i = threadIdx.x; i < nbuck; i += 256) {
        blockBaseS[(size_t)blockIdx.x * nbuck + i] = atomicAdd(&gHistS[i], hs[i]);
        blockBaseD[(size_t)blockIdx.x * nbuck + i] = atomicAdd(&gHistD[i], hd[i]);
    }
}

// single-block scan: bucketStart[0..nbuck] from gHist; optionally row_ptr[N]=E
__global__ __launch_bounds__(512) void k_part_scan(const unsigned* __restrict__ gHist, int nbuck,
                                                   unsigned* __restrict__ bucketStart,
                                                   unsigned* __restrict__ row_ptr_last, unsigned Eval) {
    __shared__ unsigned s[MAXBUCK];
    int t = threadIdx.x;
    s[t] = (t < nbuck) ? gHist[t] : 0u;
    __syncthreads();
    for (int off = 1; off < MAXBUCK; off <<= 1) {
        unsigned v = (t >= off) ? s[t - off] : 0u;
        __syncthreads();
        s[t] += v;
        __syncthreads();
    }
    if (t <= nbuck) bucketStart[t] = (t == 0) ? 0u : s[t - 1];
    if (t == 0 && row_ptr_last) *row_ptr_last = Eval;
}

// fused scatter: (src,dst) pairs into dst-buckets AND src values into src-buckets
__global__ __launch_bounds__(256) void k_part_scatter_both(const int* __restrict__ src, const int* __restrict__ dst,
                                                           int E, int nbuck,
                                                           const unsigned* __restrict__ bstartS,
                                                           const unsigned* __restrict__ bstartD,
                                                           const unsigned* __restrict__ blockBaseS,
                                                           const unsigned* __restrict__ blockBaseD,
                                                           int2* __restrict__ pairs, int* __restrict__ srcbuf) {
    __shared__ unsigned curS[MAXBUCK];
    __shared__ unsigned curD[MAXBUCK];
    for (int i = threadIdx.x; i < nbuck; i += 256) {
        curS[i] = bstartS[i] + blockBaseS[(size_t)blockIdx.x * nbuck + i];
        curD[i] = bstartD[i] + blockBaseD[(size_t)blockIdx.x * nbuck + i];
    }
    __syncthreads();
    int lo, hi;
    chunk_range(E, gridDim.x, blockIdx.x, lo, hi);
    for (int e = lo + threadIdx.x; e < hi; e += 256) {
        int s = src[e], d = dst[e];
        unsigned posD = atomicAdd(&curD[d >> 8], 1u);
        pairs[posD] = make_int2(s, d);
        unsigned posS = atomicAdd(&curS[s >> 8], 1u);
        srcbuf[posS] = s;
    }
}

// per-bucket (256 nodes): din counts, row_ptr, and csr fill — LDS atomics only
__global__ __launch_bounds__(256) void k_bucket_csr(const int2* __restrict__ pairs,
                                                    const unsigned* __restrict__ bucketStart,
                                                    unsigned* __restrict__ row_ptr,
                                                    unsigned* __restrict__ din_cnt,
                                                    int* __restrict__ csr, int n) {
    __shared__ unsigned hist[256];
    __shared__ unsigned scanw[256];
    __shared__ unsigned cur[256];
    int b = blockIdx.x, t = threadIdx.x;
    unsigned beg = bucketStart[b], end = bucketStart[b + 1];
    hist[t] = 0u;
    __syncthreads();
    for (unsigned e = beg + t; e < end; e += 256)
        atomicAdd(&hist[pairs[e].y & 255], 1u);
    __syncthreads();
    scanw[t] = hist[t];
    __syncthreads();
    for (int off = 1; off < 256; off <<= 1) {
        unsigned u = (t >= off) ? scanw[t - off] : 0u;
        __syncthreads();
        scanw[t] += u;
        __syncthreads();
    }
    unsigned excl = scanw[t] - hist[t];
    int node = (b << 8) + t;
    if (node < n) {
        row_ptr[node] = beg + excl;
        din_cnt[node] = hist[t];
    }
    cur[t] = excl;
    __syncthreads();
    for (unsigned e = beg + t; e < end; e += 256) {
        int2 p = pairs[e];
        unsigned pos = beg + atomicAdd(&cur[p.y & 255], 1u);
        csr[pos] = p.x;
    }
}

// per-bucket src-value histogram -> dout counts
__global__ __launch_bounds__(256) void k_bucket_cnt(const int* __restrict__ vals,
                                                    const unsigned* __restrict__ bucketStart,
                                                    unsigned* __restrict__ dout_cnt, int n) {
    __shared__ unsigned hist[256];
    int b = blockIdx.x, t = threadIdx.x;
    unsigned beg = bucketStart[b], end = bucketStart[b + 1];
    hist[t] = 0u;
    __syncthreads();
    for (unsigned e = beg + t; e < end; e += 256)
        atomicAdd(&hist[vals[e] & 255], 1u);
    __syncthreads();
    int node = (b << 8) + t;
    if (node < n) dout_cnt[node] = hist[t];
}

__global__ void k_invsqrt2(const unsigned* __restrict__ c0, float* __restrict__ i0,
                           const unsigned* __restrict__ c1, float* __restrict__ i1, int n) {
    int i = blockIdx.x * blockDim.x + threadIdx.x;
    if (i < n) {
        i0[i] = 1.0f / sqrtf(fmaxf((float)c0[i], 1.0f));
        i1[i] = 1.0f / sqrtf(fmaxf((float)c1[i], 1.0f));
    }
}

// ---------------- layer 1 (aggregate-first, 4-wide) ----------------

__global__ void k_prescale4(const float* __restrict__ x, const float* __restrict__ dout_is,
                            float* __restrict__ pf4, int n) {
    int i = blockIdx.x * blockDim.x + threadIdx.x;
    if (i >= n) return;
    float s = dout_is[i];
    float4 v = *reinterpret_cast<const float4*>(x + (size_t)i * 4);
    float4 o = {v.x * s, v.y * s, v.z * s, v.w * s};
    *reinterpret_cast<float4*>(pf4 + (size_t)i * 4) = o;
}

// a4[i] = dout_is[i] * din_is[i] * sum_in pf4   (the lrelu-folded prescale)
__global__ void k_gather4(const float* __restrict__ pf4, const int* __restrict__ csr,
                          const unsigned* __restrict__ row_ptr, const float* __restrict__ din_is,
                          const float* __restrict__ dout_is, float* __restrict__ a4, int n) {
    int i = blockIdx.x * blockDim.x + threadIdx.x;
    if (i >= n) return;
    unsigned beg = row_ptr[i], end = row_ptr[i + 1];
    float4 acc = {0.f, 0.f, 0.f, 0.f};
    unsigned e = beg;
    for (; e + 4 <= end; e += 4) {
        int s0 = csr[e], s1 = csr[e + 1], s2 = csr[e + 2], s3 = csr[e + 3];
        float4 v0 = *reinterpret_cast<const float4*>(pf4 + (size_t)s0 * 4);
        float4 v1 = *reinterpret_cast<const float4*>(pf4 + (size_t)s1 * 4);
        float4 v2 = *reinterpret_cast<const float4*>(pf4 + (size_t)s2 * 4);
        float4 v3 = *reinterpret_cast<const float4*>(pf4 + (size_t)s3 * 4);
        acc.x += (v0.x + v1.x) + (v2.x + v3.x);
        acc.y += (v0.y + v1.y) + (v2.y + v3.y);
        acc.z += (v0.z + v1.z) + (v2.z + v3.z);
        acc.w += (v0.w + v1.w) + (v2.w + v3.w);
    }
    for (; e < end; ++e) {
        int s = csr[e];
        float4 v = *reinterpret_cast<const float4*>(pf4 + (size_t)s * 4);
        acc.x += v.x; acc.y += v.y; acc.z += v.z; acc.w += v.w;
    }
    float sc = din_is[i] * dout_is[i];
    float4 o = {acc.x * sc, acc.y * sc, acc.z * sc, acc.w * sc};
    *reinterpret_cast<float4*>(a4 + (size_t)i * 4) = o;
}

// ---------------- fused layers 1+2 ----------------

__device__ inline float4 xp1_cols(float4 av, float ds, float4 wa, float4 wb, float4 wc, float4 wd, float4 bc) {
    float4 r;
    r.x = fmaf(av.x, wa.x, fmaf(av.y, wb.x, fmaf(av.z, wc.x, fmaf(av.w, wd.x, ds * bc.x))));
    r.y = fmaf(av.x, wa.y, fmaf(av.y, wb.y, fmaf(av.z, wc.y, fmaf(av.w, wd.y, ds * bc.y))));
    r.z = fmaf(av.x, wa.z, fmaf(av.y, wb.z, fmaf(av.z, wc.z, fmaf(av.w, wd.z, ds * bc.z))));
    r.w = fmaf(av.x, wa.w, fmaf(av.y, wb.w, fmaf(av.z, wc.w, fmaf(av.w, wd.w, ds * bc.w))));
    r.x = (r.x >= 0.f) ? r.x : LRELU_SLOPE * r.x;
    r.y = (r.y >= 0.f) ? r.y : LRELU_SLOPE * r.y;
    r.z = (r.z >= 0.f) ? r.z : LRELU_SLOPE * r.z;
    r.w = (r.w >= 0.f) ? r.w : LRELU_SLOPE * r.w;
    return r;
}

// gather recomputes xp1[s][j] = lrelu(a4[s].W1[:,j] + dout[s]*b1[j]) per edge
// (a4/dout are L2-resident: 2MB total), then GEMM with W2 as in gl128.
__global__ __launch_bounds__(512) void k_gl12(const float* __restrict__ a4,
                                              const float* __restrict__ dout_v,
                                              const int* __restrict__ csr,
                                              const unsigned* __restrict__ row_ptr,
                                              const float* __restrict__ din_is, const float* __restrict__ dout_is,
                                              const float* __restrict__ W1, const float* __restrict__ b1,
                                              const float* __restrict__ W2, const float* __restrict__ b2,
                                              float* __restrict__ xo, int n) {
    __shared__ float xs[64 * XPAD];  // 33 KB
    const int t = threadIdx.x;
    const int bbase = blockIdx.x * 64;
    const int wave = t >> 6;
    const int lane = t & 63;
    const int half = lane >> 5;
    const int j4 = (lane & 31) * 4;

    // per-lane W1 fragment: columns j4..j4+3 of the 4 rows, plus bias
    float4 wa = *reinterpret_cast<const float4*>(W1 + 0 * 128 + j4);
    float4 wb = *reinterpret_cast<const float4*>(W1 + 1 * 128 + j4);
    float4 wc = *reinterpret_cast<const float4*>(W1 + 2 * 128 + j4);
    float4 wd = *reinterpret_cast<const float4*>(W1 + 3 * 128 + j4);
    float4 bc = *reinterpret_cast<const float4*>(b1 + j4);

#pragma unroll
    for (int sweep = 0; sweep < 4; ++sweep) {
        int r = wave * 2 + half + sweep * 16;
        int node = bbase + r;
        float4 acc = {0.f, 0.f, 0.f, 0.f};
        if (node < n) {
            unsigned beg = row_ptr[node], end = row_ptr[node + 1];
            unsigned e = beg;
            for (; e + 4 <= end; e += 4) {
                int s0 = csr[e + 0], s1 = csr[e + 1], s2 = csr[e + 2], s3 = csr[e + 3];
                float4 a0 = *reinterpret_cast<const float4*>(a4 + (size_t)s0 * 4);
                float4 a1 = *reinterpret_cast<const float4*>(a4 + (size_t)s1 * 4);
                float4 a2 = *reinterpret_cast<const float4*>(a4 + (size_t)s2 * 4);
                float4 a3 = *reinterpret_cast<const float4*>(a4 + (size_t)s3 * 4);
                float d0 = dout_v[s0], d1 = dout_v[s1], d2 = dout_v[s2], d3 = dout_v[s3];
                float4 x0 = xp1_cols(a0, d0, wa, wb, wc, wd, bc);
                float4 x1 = xp1_cols(a1, d1, wa, wb, wc, wd, bc);
                float4 x2 = xp1_cols(a2, d2, wa, wb, wc, wd, bc);
                float4 x3 = xp1_cols(a3, d3, wa, wb, wc, wd, bc);
                acc.x += (x0.x + x1.x) + (x2.x + x3.x);
                acc.y += (x0.y + x1.y) + (x2.y + x3.y);
                acc.z += (x0.z + x1.z) + (x2.z + x3.z);
                acc.w += (x0.w + x1.w) + (x2.w + x3.w);
            }
            for (; e < end; ++e) {
                int s = csr[e];
                float4 av = *reinterpret_cast<const float4*>(a4 + (size_t)s * 4);
                float4 xv = xp1_cols(av, dout_v[s], wa, wb, wc, wd, bc);
                acc.x += xv.x; acc.y += xv.y; acc.z += xv.z; acc.w += xv.w;
            }
            float di = din_is[node];
            acc.x *= di; acc.y *= di; acc.z *= di; acc.w *= di;
        }
        float* d = xs + r * XPAD + j4;
        d[0] = acc.x; d[1] = acc.y; d[2] = acc.z; d[3] = acc.w;
    }
    __syncthreads();

    // GEMM phase with W2 (wave-uniform scalar loads)
    const int jg = __builtin_amdgcn_readfirstlane(wave) & 7;
    const int j0 = jg * 16;
    const float* Wj = W2 + j0;
    const float* xrow = xs + lane * XPAD;

    float acc[16];
#pragma unroll
    for (int q = 0; q < 16; ++q) acc[q] = 0.f;

#pragma unroll 2
    for (int k = 0; k < 128; k += 4) {
        float x0 = xrow[k + 0];
        float x1 = xrow[k + 1];
        float x2 = xrow[k + 2];
        float x3 = xrow[k + 3];
        const float* w0 = Wj + (size_t)k * 128;
#pragma unroll
        for (int q = 0; q < 16; ++q) {
            acc[q] += x0 * w0[q] + x1 * w0[128 + q] + x2 * w0[256 + q] + x3 * w0[384 + q];
        }
    }

    int node = bbase + lane;
    if (node < n) {
        float s = dout_is[node];
        float* out = xo + (size_t)node * 128 + j0;
#pragma unroll
        for (int q = 0; q < 16; q += 4) {
            float v0 = acc[q + 0] + b2[j0 + q + 0];
            float v1 = acc[q + 1] + b2[j0 + q + 1];
            float v2 = acc[q + 2] + b2[j0 + q + 2];
            float v3 = acc[q + 3] + b2[j0 + q + 3];
            v0 = (v0 >= 0.f) ? v0 : LRELU_SLOPE * v0;
            v1 = (v1 >= 0.f) ? v1 : LRELU_SLOPE * v1;
            v2 = (v2 >= 0.f) ? v2 : LRELU_SLOPE * v2;
            v3 = (v3 >= 0.f) ? v3 : LRELU_SLOPE * v3;
            float4 o = {v0 * s, v1 * s, v2 * s, v3 * s};
            *reinterpret_cast<float4*>(out + q) = o;
        }
    }
}

// ---------------- fused middle layer (128-wide input) ----------------

__global__ __launch_bounds__(512) void k_gl128(const float* __restrict__ xp, const int* __restrict__ csr,
                                               const unsigned* __restrict__ row_ptr,
                                               const float* __restrict__ din_is, const float* __restrict__ dout_is,
                                               const float* __restrict__ W, const float* __restrict__ b,
                                               float* __restrict__ xo, int n) {
    __shared__ float xs[64 * XPAD];  // 33 KB
    const int t = threadIdx.x;
    const int bbase = blockIdx.x * 64;
    const int wave = t >> 6;
    const int lane = t & 63;
    const int half = lane >> 5;
    const int j4 = (lane & 31) * 4;

#pragma unroll
    for (int sweep = 0; sweep < 4; ++sweep) {
        int r = wave * 2 + half + sweep * 16;
        int node = bbase + r;
        float4 accA = {0.f, 0.f, 0.f, 0.f};
        float4 accB = {0.f, 0.f, 0.f, 0.f};
        if (node < n) {
            unsigned beg = row_ptr[node], end = row_ptr[node + 1];
            unsigned e = beg;
            for (; e + 8 <= end; e += 8) {
                int s0 = csr[e + 0], s1 = csr[e + 1], s2 = csr[e + 2], s3 = csr[e + 3];
                int s4 = csr[e + 4], s5 = csr[e + 5], s6 = csr[e + 6], s7 = csr[e + 7];
                float4 v0 = *reinterpret_cast<const float4*>(xp + (size_t)s0 * 128 + j4);
                float4 v1 = *reinterpret_cast<const float4*>(xp + (size_t)s1 * 128 + j4);
                float4 v2 = *reinterpret_cast<const float4*>(xp + (size_t)s2 * 128 + j4);
                float4 v3 = *reinterpret_cast<const float4*>(xp + (size_t)s3 * 128 + j4);
                float4 v4 = *reinterpret_cast<const float4*>(xp + (size_t)s4 * 128 + j4);
                float4 v5 = *reinterpret_cast<const float4*>(xp + (size_t)s5 * 128 + j4);
                float4 v6 = *reinterpret_cast<const float4*>(xp + (size_t)s6 * 128 + j4);
                float4 v7 = *reinterpret_cast<const float4*>(xp + (size_t)s7 * 128 + j4);
                accA.x += (v0.x + v1.x) + (v2.x + v3.x);
                accA.y += (v0.y + v1.y) + (v2.y + v3.y);
                accA.z += (v0.z + v1.z) + (v2.z + v3.z);
                accA.w += (v0.w + v1.w) + (v2.w + v3.w);
                accB.x += (v4.x + v5.x) + (v6.x + v7.x);
                accB.y += (v4.y + v5.y) + (v6.y + v7.y);
                accB.z += (v4.z + v5.z) + (v6.z + v7.z);
                accB.w += (v4.w + v5.w) + (v6.w + v7.w);
            }
            if (e + 4 <= end) {
                int s0 = csr[e + 0], s1 = csr[e + 1], s2 = csr[e + 2], s3 = csr[e + 3];
                float4 v0 = *reinterpret_cast<const float4*>(xp + (size_t)s0 * 128 + j4);
                float4 v1 = *reinterpret_cast<const float4*>(xp + (size_t)s1 * 128 + j4);
                float4 v2 = *reinterpret_cast<const float4*>(xp + (size_t)s2 * 128 + j4);
                float4 v3 = *reinterpret_cast<const float4*>(xp + (size_t)s3 * 128 + j4);
                accA.x += (v0.x + v1.x) + (v2.x + v3.x);
                accA.y += (v0.y + v1.y) + (v2.y + v3.y);
                accA.z += (v0.z + v1.z) + (v2.z + v3.z);
                accA.w += (v0.w + v1.w) + (v2.w + v3.w);
                e += 4;
            }
            for (; e < end; ++e) {
                int s = csr[e];
                float4 v = *reinterpret_cast<const float4*>(xp + (size_t)s * 128 + j4);
                accB.x += v.x; accB.y += v.y; accB.z += v.z; accB.w += v.w;
            }
            float di = din_is[node];
            accA.x = (accA.x + accB.x) * di;
            accA.y = (accA.y + accB.y) * di;
            accA.z = (accA.z + accB.z) * di;
            accA.w = (accA.w + accB.w) * di;
        }
        float* d = xs + r * XPAD + j4;
        d[0] = accA.x; d[1] = accA.y; d[2] = accA.z; d[3] = accA.w;
    }
    __syncthreads();

    const int jg = __builtin_amdgcn_readfirstlane(wave) & 7;
    const int j0 = jg * 16;
    const float* Wj = W + j0;
    const float* xrow = xs + lane * XPAD;

    float acc[16];
#pragma unroll
    for (int q = 0; q < 16; ++q) acc[q] = 0.f;

#pragma unroll 2
    for (int k = 0; k < 128; k += 4) {
        float x0 = xrow[k + 0];
        float x1 = xrow[k + 1];
        float x2 = xrow[k + 2];
        float x3 = xrow[k + 3];
        const float* w0 = Wj + (size_t)k * 128;
#pragma unroll
        for (int q = 0; q < 16; ++q) {
            acc[q] += x0 * w0[q] + x1 * w0[128 + q] + x2 * w0[256 + q] + x3 * w0[384 + q];
        }
    }

    int node = bbase + lane;
    if (node < n) {
        float s = dout_is[node];
        float* out = xo + (size_t)node * 128 + j0;
#pragma unroll
        for (int q = 0; q < 16; q += 4) {
            float v0 = acc[q + 0] + b[j0 + q + 0];
            float v1 = acc[q + 1] + b[j0 + q + 1];
            float v2 = acc[q + 2] + b[j0 + q + 2];
            float v3 = acc[q + 3] + b[j0 + q + 3];
            v0 = (v0 >= 0.f) ? v0 : LRELU_SLOPE * v0;
            v1 = (v1 >= 0.f) ? v1 : LRELU_SLOPE * v1;
            v2 = (v2 >= 0.f) ? v2 : LRELU_SLOPE * v2;
            v3 = (v3 >= 0.f) ? v3 : LRELU_SLOPE * v3;
            float4 o = {v0 * s, v1 * s, v2 * s, v3 * s};
            *reinterpret_cast<float4*>(out + q) = o;
        }
    }
}

// ---------------- layer 5 ----------------

__global__ __launch_bounds__(256) void k_lin5v(const float* __restrict__ xp, const float* __restrict__ W,
                                               float* __restrict__ h, int n) {
    int node = blockIdx.x * 8 + (threadIdx.x >> 5);
    if (node >= n) return;
    int l = threadIdx.x & 31;
    int k4 = l * 4;
    float4 xv = *reinterpret_cast<const float4*>(xp + (size_t)node * 128 + k4);
    float4 wA = *reinterpret_cast<const float4*>(W + (size_t)k4 * 3);
    float4 wB = *reinterpret_cast<const float4*>(W + (size_t)k4 * 3 + 4);
    float4 wC = *reinterpret_cast<const float4*>(W + (size_t)k4 * 3 + 8);
    float p0 = xv.x * wA.x + xv.y * wA.w + xv.z * wB.z + xv.w * wC.y;
    float p1 = xv.x * wA.y + xv.y * wB.x + xv.z * wB.w + xv.w * wC.z;
    float p2 = xv.x * wA.z + xv.y * wB.y + xv.z * wC.x + xv.w * wC.w;
    for (int off = 16; off; off >>= 1) {
        p0 += __shfl_xor(p0, off, 32);
        p1 += __shfl_xor(p1, off, 32);
        p2 += __shfl_xor(p2, off, 32);
    }
    if (l == 0) {
        h[(size_t)node * 3 + 0] = p0;
        h[(size_t)node * 3 + 1] = p1;
        h[(size_t)node * 3 + 2] = p2;
    }
}

__global__ void k_gather3(const float* __restrict__ h, const int* __restrict__ csr,
                          const unsigned* __restrict__ row_ptr, const float* __restrict__ din_is,
                          const float* __restrict__ b, float* __restrict__ out, int n) {
    int i = blockIdx.x * blockDim.x + threadIdx.x;
    if (i >= n) return;
    unsigned beg = row_ptr[i], end = row_ptr[i + 1];
    float a0 = 0.f, a1 = 0.f, a2 = 0.f;
    for (unsigned e = beg; e < end; ++e) {
        int s = csr[e];
        a0 += h[(size_t)s * 3 + 0];
        a1 += h[(size_t)s * 3 + 1];
        a2 += h[(size_t)s * 3 + 2];
    }
    float di = din_is[i];
    out[(size_t)i * 3 + 0] = a0 * di + b[0];
    out[(size_t)i * 3 + 1] = a1 * di + b[1];
    out[(size_t)i * 3 + 2] = a2 * di + b[2];
}

// ---------------- launch ----------------

extern "C" void kernel_launch(void* const* d_in, const int* in_sizes, int n_in,
                              void* d_out, int out_size, void* d_ws, size_t ws_size,
                              hipStream_t stream) {
    const float* features = (const float*)d_in[0];
    const int* esrc = (const int*)d_in[1];
    const int* edst = (const int*)d_in[2];
    const float* W1 = (const float*)d_in[3];  const float* b1 = (const float*)d_in[4];
    const float* W2 = (const float*)d_in[5];  const float* b2 = (const float*)d_in[6];
    const float* W3 = (const float*)d_in[7];  const float* b3 = (const float*)d_in[8];
    const float* W4 = (const float*)d_in[9];  const float* b4 = (const float*)d_in[10];
    const float* W5 = (const float*)d_in[11]; const float* b5 = (const float*)d_in[12];

    const int N = in_sizes[0] / 4;
    const int E = in_sizes[1];
    const int nbuck = (N + 255) / 256;  // 391 for N=100K (<= MAXBUCK)
    const int NPB = 256;                // partition blocks

    size_t off = 0;
    auto carve = [&](size_t bytes) -> void* {
        void* p = (char*)d_ws + off;
        off = (off + bytes + 255) & ~(size_t)255;
        return p;
    };
    float*    A         = (float*)carve((size_t)N * 128 * 4);
    float*    B         = (float*)carve((size_t)N * 128 * 4);
    int*      csr       = (int*)carve((size_t)E * 4);
    unsigned* row_ptr   = (unsigned*)carve((size_t)(N + 1) * 4);
    unsigned* dout_cnt  = (unsigned*)carve((size_t)N * 4);
    unsigned* din_cnt   = (unsigned*)carve((size_t)N * 4);
    float*    dout_is   = (float*)carve((size_t)N * 4);
    float*    din_is    = (float*)carve((size_t)N * 4);
    unsigned* gHistD    = (unsigned*)carve((size_t)MAXBUCK * 4);
    unsigned* gHistS    = (unsigned*)carve((size_t)MAXBUCK * 4);
    unsigned* bstartD   = (unsigned*)carve((size_t)(MAXBUCK + 1) * 4);
    unsigned* bstartS   = (unsigned*)carve((size_t)(MAXBUCK + 1) * 4);
    unsigned* blockBaseD = (unsigned*)carve((size_t)NPB * nbuck * 4);
    unsigned* blockBaseS = (unsigned*)carve((size_t)NPB * nbuck * 4);
    float*    h5        = (float*)carve((size_t)N * 3 * 4);
    (void)ws_size;
    // aliases inside A (dead before A's first real use as xp2 by k_gl12):
    int2* pairs  = (int2*)A;
    int*  srcbuf = (int*)((char*)A + (size_t)E * 8);
    // aliases inside B (dead before B's first real use as xp3 by gl128-L3):
    float* pf4 = B;
    float* a4  = B + (size_t)N * 4;

    hipMemsetAsync(gHistD, 0, (size_t)MAXBUCK * 4, stream);
    hipMemsetAsync(gHistS, 0, (size_t)MAXBUCK * 4, stream);

    // ---- bucket-partition preprocessing ----
    k_part_hist2<<<NPB, 256, 0, stream>>>(esrc, edst, E, nbuck, gHistS, gHistD, blockBaseS, blockBaseD);
    k_part_scan<<<1, 512, 0, stream>>>(gHistD, nbuck, bstartD, row_ptr + N, (unsigned)E);
    k_part_scan<<<1, 512, 0, stream>>>(gHistS, nbuck, bstartS, (unsigned*)nullptr, 0u);
    k_part_scatter_both<<<NPB, 256, 0, stream>>>(esrc, edst, E, nbuck, bstartS, bstartD,
                                                 blockBaseS, blockBaseD, pairs, srcbuf);
    k_bucket_csr<<<nbuck, 256, 0, stream>>>(pairs, bstartD, row_ptr, din_cnt, csr, N);
    k_bucket_cnt<<<nbuck, 256, 0, stream>>>(srcbuf, bstartS, dout_cnt, N);
    k_invsqrt2<<<(N + 255) / 256, 256, 0, stream>>>(dout_cnt, dout_is, din_cnt, din_is, N);

    // ---- layer 1 prep: 4-wide prescale + aggregate ----
    k_prescale4<<<(N + 255) / 256, 256, 0, stream>>>(features, dout_is, pf4, N);
    k_gather4<<<(N + 255) / 256, 256, 0, stream>>>(pf4, csr, row_ptr, din_is, dout_is, a4, N);

    // ---- layers 1+2 fused (on-the-fly xp1), layers 3-4 ----
    int glGrid = (N + 63) / 64;
    k_gl12<<<glGrid, 512, 0, stream>>>(a4, dout_is, csr, row_ptr, din_is, dout_is, W1, b1, W2, b2, A, N);
    k_gl128<<<glGrid, 512, 0, stream>>>(A, csr, row_ptr, din_is, dout_is, W3, b3, B, N);
    k_gl128<<<glGrid, 512, 0, stream>>>(B, csr, row_ptr, din_is, dout_is, W4, b4, A, N);

    // ---- layer 5: 128 -> 3, then 3-wide gather ----
    k_lin5v<<<(N + 7) / 8, 256, 0, stream>>>(A, W5, h5, N);
    k_gather3<<<(N + 255) / 256, 256, 0, stream>>>(h5, csr, row_ptr, din_is, b5, (float*)d_out, N);
}

// Round 9
// 467.228 us; speedup vs baseline: 1.6193x; 1.2093x over previous
//
#include <hip/hip_runtime.h>
#include <hip/hip_fp16.h>
#include <math.h>

// GraphConv x5 (DGL norm='both') on MI355X.
// R9: layers 2/3 outputs stored as fp16 (gather operand only); gathers for
// layers 3/4 read 256B rows instead of 512B -> compulsory L2-miss bytes
// halve (377->~190MB at the measured ~2.4TB/s miss-path wall). All
// accumulation/GEMM stays fp32; only the stored intermediate is rounded
// (|xp|<~0.05, biases are zero -> added absmax ~1e-4, threshold 2.39e-4).
// Layer 2 gather recomputes xp1 on the fly from 4-wide a4 (L2-resident).
// CSR via LDS-binned bucket partition (no device-scope atomic storms).

#define LRELU_SLOPE 0.01f
#define XPAD 129     // 128+1: LDS bank (lane+k)%32 -> 2-way on wave64 = free
#define MAXBUCK 512  // supports N <= 131072

// ---------------- bucket-partition preprocessing ----------------

__device__ inline void chunk_range(int E, int nchunks, int cid, int& lo, int& hi) {
    int chunk = (E + nchunks - 1) / nchunks;
    lo = cid * chunk;
    hi = min(E, lo + chunk);
}

__global__ __launch_bounds__(256) void k_part_hist2(const int* __restrict__ src, const int* __restrict__ dst,
                                                    int E, int nbuck,
                                                    unsigned* __restrict__ gHistS, unsigned* __restrict__ gHistD,
                                                    unsigned* __restrict__ blockBaseS, unsigned* __restrict__ blockBaseD) {
    __shared__ unsigned hs[MAXBUCK];
    __shared__ unsigned hd[MAXBUCK];
    for (int i = threadIdx.x; i < nbuck; i += 256) { hs[i] = 0u; hd[i] = 0u; }
    __syncthreads();
    int lo, hi;
    chunk_range(E, gridDim.x, blockIdx.x, lo, hi);
    for (int e = lo + threadIdx.x; e < hi; e += 256) {
        atomicAdd(&hs[src[e] >> 8], 1u);
        atomicAdd(&hd[dst[e] >> 8], 1u);
    }
    __syncthreads();
    for (int i = threadIdx.x; i < nbuck; i += 256) {
        blockBaseS[(size_t)blockIdx.x * nbuck + i] = atomicAdd(&gHistS[i], hs[i]);
        blockBaseD[(size_t)blockIdx.x * nbuck + i] = atomicAdd(&gHistD[i], hd[i]);
    }
}

__global__ __launch_bounds__(512) void k_part_scan(const unsigned* __restrict__ gHist, int nbuck,
                                                   unsigned* __restrict__ bucketStart,
                                                   unsigned* __restrict__ row_ptr_last, unsigned Eval) {
    __shared__ unsigned s[MAXBUCK];
    int t = threadIdx.x;
    s[t] = (t < nbuck) ? gHist[t] : 0u;
    __syncthreads();
    for (int off = 1; off < MAXBUCK; off <<= 1) {
        unsigned v = (t >= off) ? s[t - off] : 0u;
        __syncthreads();
        s[t] += v;
        __syncthreads();
    }
    if (t <= nbuck) bucketStart[t] = (t == 0) ? 0u : s[t - 1];
    if (t == 0 && row_ptr_last) *row_ptr_last = Eval;
}

__global__ __launch_bounds__(256) void k_part_scatter_both(const int* __restrict__ src, const int* __restrict__ dst,
                                                           int E, int nbuck,
                                                           const unsigned* __restrict__ bstartS,
                                                           const unsigned* __restrict__ bstartD,
                                                           const unsigned* __restrict__ blockBaseS,
                                                           const unsigned* __restrict__ blockBaseD,
                                                           int2* __restrict__ pairs, int* __restrict__ srcbuf) {
    __shared__ unsigned curS[MAXBUCK];
    __shared__ unsigned curD[MAXBUCK];
    for (int i = threadIdx.x; i < nbuck; i += 256) {
        curS[i] = bstartS[i] + blockBaseS[(size_t)blockIdx.x * nbuck + i];
        curD[i] = bstartD[i] + blockBaseD[(size_t)blockIdx.x * nbuck + i];
    }
    __syncthreads();
    int lo, hi;
    chunk_range(E, gridDim.x, blockIdx.x, lo, hi);
    for (int e = lo + threadIdx.x; e < hi; e += 256) {
        int s = src[e], d = dst[e];
        unsigned posD = atomicAdd(&curD[d >> 8], 1u);
        pairs[posD] = make_int2(s, d);
        unsigned posS = atomicAdd(&curS[s >> 8], 1u);
        srcbuf[posS] = s;
    }
}

__global__ __launch_bounds__(256) void k_bucket_csr(const int2* __restrict__ pairs,
                                                    const unsigned* __restrict__ bucketStart,
                                                    unsigned* __restrict__ row_ptr,
                                                    unsigned* __restrict__ din_cnt,
                                                    int* __restrict__ csr, int n) {
    __shared__ unsigned hist[256];
    __shared__ unsigned scanw[256];
    __shared__ unsigned cur[256];
    int b = blockIdx.x, t = threadIdx.x;
    unsigned beg = bucketStart[b], end = bucketStart[b + 1];
    hist[t] = 0u;
    __syncthreads();
    for (unsigned e = beg + t; e < end; e += 256)
        atomicAdd(&hist[pairs[e].y & 255], 1u);
    __syncthreads();
    scanw[t] = hist[t];
    __syncthreads();
    for (int off = 1; off < 256; off <<= 1) {
        unsigned u = (t >= off) ? scanw[t - off] : 0u;
        __syncthreads();
        scanw[t] += u;
        __syncthreads();
    }
    unsigned excl = scanw[t] - hist[t];
    int node = (b << 8) + t;
    if (node < n) {
        row_ptr[node] = beg + excl;
        din_cnt[node] = hist[t];
    }
    cur[t] = excl;
    __syncthreads();
    for (unsigned e = beg + t; e < end; e += 256) {
        int2 p = pairs[e];
        unsigned pos = beg + atomicAdd(&cur[p.y & 255], 1u);
        csr[pos] = p.x;
    }
}

__global__ __launch_bounds__(256) void k_bucket_cnt(const int* __restrict__ vals,
                                                    const unsigned* __restrict__ bucketStart,
                                                    unsigned* __restrict__ dout_cnt, int n) {
    __shared__ unsigned hist[256];
    int b = blockIdx.x, t = threadIdx.x;
    unsigned beg = bucketStart[b], end = bucketStart[b + 1];
    hist[t] = 0u;
    __syncthreads();
    for (unsigned e = beg + t; e < end; e += 256)
        atomicAdd(&hist[vals[e] & 255], 1u);
    __syncthreads();
    int node = (b << 8) + t;
    if (node < n) dout_cnt[node] = hist[t];
}

__global__ void k_invsqrt2(const unsigned* __restrict__ c0, float* __restrict__ i0,
                           const unsigned* __restrict__ c1, float* __restrict__ i1, int n) {
    int i = blockIdx.x * blockDim.x + threadIdx.x;
    if (i < n) {
        i0[i] = 1.0f / sqrtf(fmaxf((float)c0[i], 1.0f));
        i1[i] = 1.0f / sqrtf(fmaxf((float)c1[i], 1.0f));
    }
}

// ---------------- layer 1 (aggregate-first, 4-wide) ----------------

__global__ void k_prescale4(const float* __restrict__ x, const float* __restrict__ dout_is,
                            float* __restrict__ pf4, int n) {
    int i = blockIdx.x * blockDim.x + threadIdx.x;
    if (i >= n) return;
    float s = dout_is[i];
    float4 v = *reinterpret_cast<const float4*>(x + (size_t)i * 4);
    float4 o = {v.x * s, v.y * s, v.z * s, v.w * s};
    *reinterpret_cast<float4*>(pf4 + (size_t)i * 4) = o;
}

// a4[i] = dout_is[i] * din_is[i] * sum_in pf4
__global__ void k_gather4(const float* __restrict__ pf4, const int* __restrict__ csr,
                          const unsigned* __restrict__ row_ptr, const float* __restrict__ din_is,
                          const float* __restrict__ dout_is, float* __restrict__ a4, int n) {
    int i = blockIdx.x * blockDim.x + threadIdx.x;
    if (i >= n) return;
    unsigned beg = row_ptr[i], end = row_ptr[i + 1];
    float4 acc = {0.f, 0.f, 0.f, 0.f};
    unsigned e = beg;
    for (; e + 4 <= end; e += 4) {
        int s0 = csr[e], s1 = csr[e + 1], s2 = csr[e + 2], s3 = csr[e + 3];
        float4 v0 = *reinterpret_cast<const float4*>(pf4 + (size_t)s0 * 4);
        float4 v1 = *reinterpret_cast<const float4*>(pf4 + (size_t)s1 * 4);
        float4 v2 = *reinterpret_cast<const float4*>(pf4 + (size_t)s2 * 4);
        float4 v3 = *reinterpret_cast<const float4*>(pf4 + (size_t)s3 * 4);
        acc.x += (v0.x + v1.x) + (v2.x + v3.x);
        acc.y += (v0.y + v1.y) + (v2.y + v3.y);
        acc.z += (v0.z + v1.z) + (v2.z + v3.z);
        acc.w += (v0.w + v1.w) + (v2.w + v3.w);
    }
    for (; e < end; ++e) {
        int s = csr[e];
        float4 v = *reinterpret_cast<const float4*>(pf4 + (size_t)s * 4);
        acc.x += v.x; acc.y += v.y; acc.z += v.z; acc.w += v.w;
    }
    float sc = din_is[i] * dout_is[i];
    float4 o = {acc.x * sc, acc.y * sc, acc.z * sc, acc.w * sc};
    *reinterpret_cast<float4*>(a4 + (size_t)i * 4) = o;
}

// ---------------- fp16 helpers ----------------

__device__ inline float4 ldh4(const __half* p) {
    uint2 u = *reinterpret_cast<const uint2*>(p);
    __half2 h0 = *reinterpret_cast<const __half2*>(&u.x);
    __half2 h1 = *reinterpret_cast<const __half2*>(&u.y);
    float2 a = __half22float2(h0);
    float2 b = __half22float2(h1);
    return make_float4(a.x, a.y, b.x, b.y);
}

__device__ inline void sth16(__half* p, const float* v) {
    __half2 hh[8];
#pragma unroll
    for (int q = 0; q < 8; ++q) hh[q] = __floats2half2_rn(v[2 * q], v[2 * q + 1]);
    const float4* f = reinterpret_cast<const float4*>(&hh[0]);
    *reinterpret_cast<float4*>(p) = f[0];
    *reinterpret_cast<float4*>(p + 8) = f[1];
}

// ---------------- fused layers 1+2 (fp16 out) ----------------

__device__ inline float4 xp1_cols(float4 av, float ds, float4 wa, float4 wb, float4 wc, float4 wd, float4 bc) {
    float4 r;
    r.x = fmaf(av.x, wa.x, fmaf(av.y, wb.x, fmaf(av.z, wc.x, fmaf(av.w, wd.x, ds * bc.x))));
    r.y = fmaf(av.x, wa.y, fmaf(av.y, wb.y, fmaf(av.z, wc.y, fmaf(av.w, wd.y, ds * bc.y))));
    r.z = fmaf(av.x, wa.z, fmaf(av.y, wb.z, fmaf(av.z, wc.z, fmaf(av.w, wd.z, ds * bc.z))));
    r.w = fmaf(av.x, wa.w, fmaf(av.y, wb.w, fmaf(av.z, wc.w, fmaf(av.w, wd.w, ds * bc.w))));
    r.x = (r.x >= 0.f) ? r.x : LRELU_SLOPE * r.x;
    r.y = (r.y >= 0.f) ? r.y : LRELU_SLOPE * r.y;
    r.z = (r.z >= 0.f) ? r.z : LRELU_SLOPE * r.z;
    r.w = (r.w >= 0.f) ? r.w : LRELU_SLOPE * r.w;
    return r;
}

__global__ __launch_bounds__(512) void k_gl12(const float* __restrict__ a4,
                                              const float* __restrict__ dout_v,
                                              const int* __restrict__ csr,
                                              const unsigned* __restrict__ row_ptr,
                                              const float* __restrict__ din_is, const float* __restrict__ dout_is,
                                              const float* __restrict__ W1, const float* __restrict__ b1,
                                              const float* __restrict__ W2, const float* __restrict__ b2,
                                              __half* __restrict__ xh_out, int n) {
    __shared__ float xs[64 * XPAD];  // 33 KB
    const int t = threadIdx.x;
    const int bbase = blockIdx.x * 64;
    const int wave = t >> 6;
    const int lane = t & 63;
    const int half = lane >> 5;
    const int j4 = (lane & 31) * 4;

    float4 wa = *reinterpret_cast<const float4*>(W1 + 0 * 128 + j4);
    float4 wb = *reinterpret_cast<const float4*>(W1 + 1 * 128 + j4);
    float4 wc = *reinterpret_cast<const float4*>(W1 + 2 * 128 + j4);
    float4 wd = *reinterpret_cast<const float4*>(W1 + 3 * 128 + j4);
    float4 bc = *reinterpret_cast<const float4*>(b1 + j4);

#pragma unroll
    for (int sweep = 0; sweep < 4; ++sweep) {
        int r = wave * 2 + half + sweep * 16;
        int node = bbase + r;
        float4 acc = {0.f, 0.f, 0.f, 0.f};
        if (node < n) {
            unsigned beg = row_ptr[node], end = row_ptr[node + 1];
            unsigned e = beg;
            for (; e + 4 <= end; e += 4) {
                int s0 = csr[e + 0], s1 = csr[e + 1], s2 = csr[e + 2], s3 = csr[e + 3];
                float4 a0 = *reinterpret_cast<const float4*>(a4 + (size_t)s0 * 4);
                float4 a1 = *reinterpret_cast<const float4*>(a4 + (size_t)s1 * 4);
                float4 a2 = *reinterpret_cast<const float4*>(a4 + (size_t)s2 * 4);
                float4 a3 = *reinterpret_cast<const float4*>(a4 + (size_t)s3 * 4);
                float d0 = dout_v[s0], d1 = dout_v[s1], d2 = dout_v[s2], d3 = dout_v[s3];
                float4 x0 = xp1_cols(a0, d0, wa, wb, wc, wd, bc);
                float4 x1 = xp1_cols(a1, d1, wa, wb, wc, wd, bc);
                float4 x2 = xp1_cols(a2, d2, wa, wb, wc, wd, bc);
                float4 x3 = xp1_cols(a3, d3, wa, wb, wc, wd, bc);
                acc.x += (x0.x + x1.x) + (x2.x + x3.x);
                acc.y += (x0.y + x1.y) + (x2.y + x3.y);
                acc.z += (x0.z + x1.z) + (x2.z + x3.z);
                acc.w += (x0.w + x1.w) + (x2.w + x3.w);
            }
            for (; e < end; ++e) {
                int s = csr[e];
                float4 av = *reinterpret_cast<const float4*>(a4 + (size_t)s * 4);
                float4 xv = xp1_cols(av, dout_v[s], wa, wb, wc, wd, bc);
                acc.x += xv.x; acc.y += xv.y; acc.z += xv.z; acc.w += xv.w;
            }
            float di = din_is[node];
            acc.x *= di; acc.y *= di; acc.z *= di; acc.w *= di;
        }
        float* d = xs + r * XPAD + j4;
        d[0] = acc.x; d[1] = acc.y; d[2] = acc.z; d[3] = acc.w;
    }
    __syncthreads();

    const int jg = __builtin_amdgcn_readfirstlane(wave) & 7;
    const int j0 = jg * 16;
    const float* Wj = W2 + j0;
    const float* xrow = xs + lane * XPAD;

    float acc[16];
#pragma unroll
    for (int q = 0; q < 16; ++q) acc[q] = 0.f;

#pragma unroll 2
    for (int k = 0; k < 128; k += 4) {
        float x0 = xrow[k + 0];
        float x1 = xrow[k + 1];
        float x2 = xrow[k + 2];
        float x3 = xrow[k + 3];
        const float* w0 = Wj + (size_t)k * 128;
#pragma unroll
        for (int q = 0; q < 16; ++q) {
            acc[q] += x0 * w0[q] + x1 * w0[128 + q] + x2 * w0[256 + q] + x3 * w0[384 + q];
        }
    }

    int node = bbase + lane;
    if (node < n) {
        float s = dout_is[node];
        float v[16];
#pragma unroll
        for (int q = 0; q < 16; ++q) {
            float u = acc[q] + b2[j0 + q];
            u = (u >= 0.f) ? u : LRELU_SLOPE * u;
            v[q] = u * s;
        }
        sth16(xh_out + (size_t)node * 128 + j0, v);
    }
}

// ---------------- fused middle layer (fp16 gather operand) ----------------

__global__ __launch_bounds__(512) void k_gl128h(const __half* __restrict__ xh, const int* __restrict__ csr,
                                                const unsigned* __restrict__ row_ptr,
                                                const float* __restrict__ din_is, const float* __restrict__ dout_is,
                                                const float* __restrict__ W, const float* __restrict__ b,
                                                __half* __restrict__ xh_out, float* __restrict__ xo32, int n) {
    __shared__ float xs[64 * XPAD];  // 33 KB
    const int t = threadIdx.x;
    const int bbase = blockIdx.x * 64;
    const int wave = t >> 6;
    const int lane = t & 63;
    const int half = lane >> 5;
    const int j4 = (lane & 31) * 4;

#pragma unroll
    for (int sweep = 0; sweep < 4; ++sweep) {
        int r = wave * 2 + half + sweep * 16;
        int node = bbase + r;
        float4 accA = {0.f, 0.f, 0.f, 0.f};
        float4 accB = {0.f, 0.f, 0.f, 0.f};
        if (node < n) {
            unsigned beg = row_ptr[node], end = row_ptr[node + 1];
            unsigned e = beg;
            for (; e + 8 <= end; e += 8) {
                int s0 = csr[e + 0], s1 = csr[e + 1], s2 = csr[e + 2], s3 = csr[e + 3];
                int s4 = csr[e + 4], s5 = csr[e + 5], s6 = csr[e + 6], s7 = csr[e + 7];
                float4 v0 = ldh4(xh + (size_t)s0 * 128 + j4);
                float4 v1 = ldh4(xh + (size_t)s1 * 128 + j4);
                float4 v2 = ldh4(xh + (size_t)s2 * 128 + j4);
                float4 v3 = ldh4(xh + (size_t)s3 * 128 + j4);
                float4 v4 = ldh4(xh + (size_t)s4 * 128 + j4);
                float4 v5 = ldh4(xh + (size_t)s5 * 128 + j4);
                float4 v6 = ldh4(xh + (size_t)s6 * 128 + j4);
                float4 v7 = ldh4(xh + (size_t)s7 * 128 + j4);
                accA.x += (v0.x + v1.x) + (v2.x + v3.x);
                accA.y += (v0.y + v1.y) + (v2.y + v3.y);
                accA.z += (v0.z + v1.z) + (v2.z + v3.z);
                accA.w += (v0.w + v1.w) + (v2.w + v3.w);
                accB.x += (v4.x + v5.x) + (v6.x + v7.x);
                accB.y += (v4.y + v5.y) + (v6.y + v7.y);
                accB.z += (v4.z + v5.z) + (v6.z + v7.z);
                accB.w += (v4.w + v5.w) + (v6.w + v7.w);
            }
            if (e + 4 <= end) {
                int s0 = csr[e + 0], s1 = csr[e + 1], s2 = csr[e + 2], s3 = csr[e + 3];
                float4 v0 = ldh4(xh + (size_t)s0 * 128 + j4);
                float4 v1 = ldh4(xh + (size_t)s1 * 128 + j4);
                float4 v2 = ldh4(xh + (size_t)s2 * 128 + j4);
                float4 v3 = ldh4(xh + (size_t)s3 * 128 + j4);
                accA.x += (v0.x + v1.x) + (v2.x + v3.x);
                accA.y += (v0.y + v1.y) + (v2.y + v3.y);
                accA.z += (v0.z + v1.z) + (v2.z + v3.z);
                accA.w += (v0.w + v1.w) + (v2.w + v3.w);
                e += 4;
            }
            for (; e < end; ++e) {
                int s = csr[e];
                float4 v = ldh4(xh + (size_t)s * 128 + j4);
                accB.x += v.x; accB.y += v.y; accB.z += v.z; accB.w += v.w;
            }
            float di = din_is[node];
            accA.x = (accA.x + accB.x) * di;
            accA.y = (accA.y + accB.y) * di;
            accA.z = (accA.z + accB.z) * di;
            accA.w = (accA.w + accB.w) * di;
        }
        float* d = xs + r * XPAD + j4;
        d[0] = accA.x; d[1] = accA.y; d[2] = accA.z; d[3] = accA.w;
    }
    __syncthreads();

    const int jg = __builtin_amdgcn_readfirstlane(wave) & 7;
    const int j0 = jg * 16;
    const float* Wj = W + j0;
    const float* xrow = xs + lane * XPAD;

    float acc[16];
#pragma unroll
    for (int q = 0; q < 16; ++q) acc[q] = 0.f;

#pragma unroll 2
    for (int k = 0; k < 128; k += 4) {
        float x0 = xrow[k + 0];
        float x1 = xrow[k + 1];
        float x2 = xrow[k + 2];
        float x3 = xrow[k + 3];
        const float* w0 = Wj + (size_t)k * 128;
#pragma unroll
        for (int q = 0; q < 16; ++q) {
            acc[q] += x0 * w0[q] + x1 * w0[128 + q] + x2 * w0[256 + q] + x3 * w0[384 + q];
        }
    }

    int node = bbase + lane;
    if (node < n) {
        float s = dout_is[node];
        float v[16];
#pragma unroll
        for (int q = 0; q < 16; ++q) {
            float u = acc[q] + b[j0 + q];
            u = (u >= 0.f) ? u : LRELU_SLOPE * u;
            v[q] = u * s;
        }
        if (xh_out) sth16(xh_out + (size_t)node * 128 + j0, v);
        if (xo32) {
            float* out = xo32 + (size_t)node * 128 + j0;
#pragma unroll
            for (int q = 0; q < 16; q += 4) {
                float4 o = {v[q], v[q + 1], v[q + 2], v[q + 3]};
                *reinterpret_cast<float4*>(out + q) = o;
            }
        }
    }
}

// ---------------- layer 5 ----------------

__global__ __launch_bounds__(256) void k_lin5v(const float* __restrict__ xp, const float* __restrict__ W,
                                               float* __restrict__ h, int n) {
    int node = blockIdx.x * 8 + (threadIdx.x >> 5);
    if (node >= n) return;
    int l = threadIdx.x & 31;
    int k4 = l * 4;
    float4 xv = *reinterpret_cast<const float4*>(xp + (size_t)node * 128 + k4);
    float4 wA = *reinterpret_cast<const float4*>(W + (size_t)k4 * 3);
    float4 wB = *reinterpret_cast<const float4*>(W + (size_t)k4 * 3 + 4);
    float4 wC = *reinterpret_cast<const float4*>(W + (size_t)k4 * 3 + 8);
    float p0 = xv.x * wA.x + xv.y * wA.w + xv.z * wB.z + xv.w * wC.y;
    float p1 = xv.x * wA.y + xv.y * wB.x + xv.z * wB.w + xv.w * wC.z;
    float p2 = xv.x * wA.z + xv.y * wB.y + xv.z * wC.x + xv.w * wC.w;
    for (int off = 16; off; off >>= 1) {
        p0 += __shfl_xor(p0, off, 32);
        p1 += __shfl_xor(p1, off, 32);
        p2 += __shfl_xor(p2, off, 32);
    }
    if (l == 0) {
        h[(size_t)node * 3 + 0] = p0;
        h[(size_t)node * 3 + 1] = p1;
        h[(size_t)node * 3 + 2] = p2;
    }
}

__global__ void k_gather3(const float* __restrict__ h, const int* __restrict__ csr,
                          const unsigned* __restrict__ row_ptr, const float* __restrict__ din_is,
                          const float* __restrict__ b, float* __restrict__ out, int n) {
    int i = blockIdx.x * blockDim.x + threadIdx.x;
    if (i >= n) return;
    unsigned beg = row_ptr[i], end = row_ptr[i + 1];
    float a0 = 0.f, a1 = 0.f, a2 = 0.f;
    for (unsigned e = beg; e < end; ++e) {
        int s = csr[e];
        a0 += h[(size_t)s * 3 + 0];
        a1 += h[(size_t)s * 3 + 1];
        a2 += h[(size_t)s * 3 + 2];
    }
    float di = din_is[i];
    out[(size_t)i * 3 + 0] = a0 * di + b[0];
    out[(size_t)i * 3 + 1] = a1 * di + b[1];
    out[(size_t)i * 3 + 2] = a2 * di + b[2];
}

// ---------------- launch ----------------

extern "C" void kernel_launch(void* const* d_in, const int* in_sizes, int n_in,
                              void* d_out, int out_size, void* d_ws, size_t ws_size,
                              hipStream_t stream) {
    const float* features = (const float*)d_in[0];
    const int* esrc = (const int*)d_in[1];
    const int* edst = (const int*)d_in[2];
    const float* W1 = (const float*)d_in[3];  const float* b1 = (const float*)d_in[4];
    const float* W2 = (const float*)d_in[5];  const float* b2 = (const float*)d_in[6];
    const float* W3 = (const float*)d_in[7];  const float* b3 = (const float*)d_in[8];
    const float* W4 = (const float*)d_in[9];  const float* b4 = (const float*)d_in[10];
    const float* W5 = (const float*)d_in[11]; const float* b5 = (const float*)d_in[12];

    const int N = in_sizes[0] / 4;
    const int E = in_sizes[1];
    const int nbuck = (N + 255) / 256;
    const int NPB = 256;

    size_t off = 0;
    auto carve = [&](size_t bytes) -> void* {
        void* p = (char*)d_ws + off;
        off = (off + bytes + 255) & ~(size_t)255;
        return p;
    };
    float*    A         = (float*)carve((size_t)N * 128 * 4);   // pairs/srcbuf alias; L4 fp32 out
    float*    Bp        = (float*)carve((size_t)N * 8 * 4);     // pf4 + a4
    __half*   xh2       = (__half*)carve((size_t)N * 128 * 2);
    __half*   xh3       = (__half*)carve((size_t)N * 128 * 2);
    int*      csr       = (int*)carve((size_t)E * 4);
    unsigned* row_ptr   = (unsigned*)carve((size_t)(N + 1) * 4);
    unsigned* dout_cnt  = (unsigned*)carve((size_t)N * 4);
    unsigned* din_cnt   = (unsigned*)carve((size_t)N * 4);
    float*    dout_is   = (float*)carve((size_t)N * 4);
    float*    din_is    = (float*)carve((size_t)N * 4);
    unsigned* gHistD    = (unsigned*)carve((size_t)MAXBUCK * 4);
    unsigned* gHistS    = (unsigned*)carve((size_t)MAXBUCK * 4);
    unsigned* bstartD   = (unsigned*)carve((size_t)(MAXBUCK + 1) * 4);
    unsigned* bstartS   = (unsigned*)carve((size_t)(MAXBUCK + 1) * 4);
    unsigned* blockBaseD = (unsigned*)carve((size_t)NPB * nbuck * 4);
    unsigned* blockBaseS = (unsigned*)carve((size_t)NPB * nbuck * 4);
    float*    h5        = (float*)carve((size_t)N * 3 * 4);
    (void)ws_size;
    // aliases inside A (dead before A's first real use as L4 output):
    int2* pairs  = (int2*)A;
    int*  srcbuf = (int*)((char*)A + (size_t)E * 8);
    float* pf4 = Bp;
    float* a4  = Bp + (size_t)N * 4;

    hipMemsetAsync(gHistD, 0, (size_t)MAXBUCK * 4, stream);
    hipMemsetAsync(gHistS, 0, (size_t)MAXBUCK * 4, stream);

    // ---- bucket-partition preprocessing ----
    k_part_hist2<<<NPB, 256, 0, stream>>>(esrc, edst, E, nbuck, gHistS, gHistD, blockBaseS, blockBaseD);
    k_part_scan<<<1, 512, 0, stream>>>(gHistD, nbuck, bstartD, row_ptr + N, (unsigned)E);
    k_part_scan<<<1, 512, 0, stream>>>(gHistS, nbuck, bstartS, (unsigned*)nullptr, 0u);
    k_part_scatter_both<<<NPB, 256, 0, stream>>>(esrc, edst, E, nbuck, bstartS, bstartD,
                                                 blockBaseS, blockBaseD, pairs, srcbuf);
    k_bucket_csr<<<nbuck, 256, 0, stream>>>(pairs, bstartD, row_ptr, din_cnt, csr, N);
    k_bucket_cnt<<<nbuck, 256, 0, stream>>>(srcbuf, bstartS, dout_cnt, N);
    k_invsqrt2<<<(N + 255) / 256, 256, 0, stream>>>(dout_cnt, dout_is, din_cnt, din_is, N);

    // ---- layer 1 prep: 4-wide prescale + aggregate ----
    k_prescale4<<<(N + 255) / 256, 256, 0, stream>>>(features, dout_is, pf4, N);
    k_gather4<<<(N + 255) / 256, 256, 0, stream>>>(pf4, csr, row_ptr, din_is, dout_is, a4, N);

    // ---- layers 1+2 fused -> fp16; layers 3-4 fp16-gather ----
    int glGrid = (N + 63) / 64;
    k_gl12<<<glGrid, 512, 0, stream>>>(a4, dout_is, csr, row_ptr, din_is, dout_is, W1, b1, W2, b2, xh2, N);
    k_gl128h<<<glGrid, 512, 0, stream>>>(xh2, csr, row_ptr, din_is, dout_is, W3, b3, xh3, (float*)nullptr, N);
    k_gl128h<<<glGrid, 512, 0, stream>>>(xh3, csr, row_ptr, din_is, dout_is, W4, b4, (__half*)nullptr, A, N);

    // ---- layer 5: 128 -> 3, then 3-wide gather ----
    k_lin5v<<<(N + 7) / 8, 256, 0, stream>>>(A, W5, h5, N);
    k_gather3<<<(N + 255) / 256, 256, 0, stream>>>(h5, csr, row_ptr, din_is, b5, (float*)d_out, N);
}

// Round 10
// 437.322 us; speedup vs baseline: 1.7300x; 1.0684x over previous
//
#include <hip/hip_runtime.h>
#include <hip/hip_fp16.h>
#include <math.h>

// GraphConv x5 (DGL norm='both') on MI355X.
// R10: (1) fp16 gathers use paired-edge dwordx4 loads (2 edges per 32-lane
// group, 16B/lane) + shfl_xor(16) merge -> half the VMEM instructions,
// 2x in-flight miss bytes (R9 showed 1.36 TB/s < 2.26 TB/s wall = issue-
// limited). (2) Layer-5 GEMM fused into L4 epilogue (LDS cross-wave
// reduce -> h5) -> kills lin5v + 100MB of xp4 traffic.

#define LRELU_SLOPE 0.01f
#define XPAD 129     // 128+1: LDS bank (lane+k)%32 -> 2-way on wave64 = free
#define MAXBUCK 512  // supports N <= 131072

// ---------------- bucket-partition preprocessing ----------------

__device__ inline void chunk_range(int E, int nchunks, int cid, int& lo, int& hi) {
    int chunk = (E + nchunks - 1) / nchunks;
    lo = cid * chunk;
    hi = min(E, lo + chunk);
}

__global__ __launch_bounds__(256) void k_part_hist2(const int* __restrict__ src, const int* __restrict__ dst,
                                                    int E, int nbuck,
                                                    unsigned* __restrict__ gHistS, unsigned* __restrict__ gHistD,
                                                    unsigned* __restrict__ blockBaseS, unsigned* __restrict__ blockBaseD) {
    __shared__ unsigned hs[MAXBUCK];
    __shared__ unsigned hd[MAXBUCK];
    for (int i = threadIdx.x; i < nbuck; i += 256) { hs[i] = 0u; hd[i] = 0u; }
    __syncthreads();
    int lo, hi;
    chunk_range(E, gridDim.x, blockIdx.x, lo, hi);
    for (int e = lo + threadIdx.x; e < hi; e += 256) {
        atomicAdd(&hs[src[e] >> 8], 1u);
        atomicAdd(&hd[dst[e] >> 8], 1u);
    }
    __syncthreads();
    for (int i = threadIdx.x; i < nbuck; i += 256) {
        blockBaseS[(size_t)blockIdx.x * nbuck + i] = atomicAdd(&gHistS[i], hs[i]);
        blockBaseD[(size_t)blockIdx.x * nbuck + i] = atomicAdd(&gHistD[i], hd[i]);
    }
}

__global__ __launch_bounds__(512) void k_part_scan(const unsigned* __restrict__ gHist, int nbuck,
                                                   unsigned* __restrict__ bucketStart,
                                                   unsigned* __restrict__ row_ptr_last, unsigned Eval) {
    __shared__ unsigned s[MAXBUCK];
    int t = threadIdx.x;
    s[t] = (t < nbuck) ? gHist[t] : 0u;
    __syncthreads();
    for (int off = 1; off < MAXBUCK; off <<= 1) {
        unsigned v = (t >= off) ? s[t - off] : 0u;
        __syncthreads();
        s[t] += v;
        __syncthreads();
    }
    if (t <= nbuck) bucketStart[t] = (t == 0) ? 0u : s[t - 1];
    if (t == 0 && row_ptr_last) *row_ptr_last = Eval;
}

__global__ __launch_bounds__(256) void k_part_scatter_both(const int* __restrict__ src, const int* __restrict__ dst,
                                                           int E, int nbuck,
                                                           const unsigned* __restrict__ bstartS,
                                                           const unsigned* __restrict__ bstartD,
                                                           const unsigned* __restrict__ blockBaseS,
                                                           const unsigned* __restrict__ blockBaseD,
                                                           int2* __restrict__ pairs, int* __restrict__ srcbuf) {
    __shared__ unsigned curS[MAXBUCK];
    __shared__ unsigned curD[MAXBUCK];
    for (int i = threadIdx.x; i < nbuck; i += 256) {
        curS[i] = bstartS[i] + blockBaseS[(size_t)blockIdx.x * nbuck + i];
        curD[i] = bstartD[i] + blockBaseD[(size_t)blockIdx.x * nbuck + i];
    }
    __syncthreads();
    int lo, hi;
    chunk_range(E, gridDim.x, blockIdx.x, lo, hi);
    for (int e = lo + threadIdx.x; e < hi; e += 256) {
        int s = src[e], d = dst[e];
        unsigned posD = atomicAdd(&curD[d >> 8], 1u);
        pairs[posD] = make_int2(s, d);
        unsigned posS = atomicAdd(&curS[s >> 8], 1u);
        srcbuf[posS] = s;
    }
}

__global__ __launch_bounds__(256) void k_bucket_csr(const int2* __restrict__ pairs,
                                                    const unsigned* __restrict__ bucketStart,
                                                    unsigned* __restrict__ row_ptr,
                                                    unsigned* __restrict__ din_cnt,
                                                    int* __restrict__ csr, int n) {
    __shared__ unsigned hist[256];
    __shared__ unsigned scanw[256];
    __shared__ unsigned cur[256];
    int b = blockIdx.x, t = threadIdx.x;
    unsigned beg = bucketStart[b], end = bucketStart[b + 1];
    hist[t] = 0u;
    __syncthreads();
    for (unsigned e = beg + t; e < end; e += 256)
        atomicAdd(&hist[pairs[e].y & 255], 1u);
    __syncthreads();
    scanw[t] = hist[t];
    __syncthreads();
    for (int off = 1; off < 256; off <<= 1) {
        unsigned u = (t >= off) ? scanw[t - off] : 0u;
        __syncthreads();
        scanw[t] += u;
        __syncthreads();
    }
    unsigned excl = scanw[t] - hist[t];
    int node = (b << 8) + t;
    if (node < n) {
        row_ptr[node] = beg + excl;
        din_cnt[node] = hist[t];
    }
    cur[t] = excl;
    __syncthreads();
    for (unsigned e = beg + t; e < end; e += 256) {
        int2 p = pairs[e];
        unsigned pos = beg + atomicAdd(&cur[p.y & 255], 1u);
        csr[pos] = p.x;
    }
}

__global__ __launch_bounds__(256) void k_bucket_cnt(const int* __restrict__ vals,
                                                    const unsigned* __restrict__ bucketStart,
                                                    unsigned* __restrict__ dout_cnt, int n) {
    __shared__ unsigned hist[256];
    int b = blockIdx.x, t = threadIdx.x;
    unsigned beg = bucketStart[b], end = bucketStart[b + 1];
    hist[t] = 0u;
    __syncthreads();
    for (unsigned e = beg + t; e < end; e += 256)
        atomicAdd(&hist[vals[e] & 255], 1u);
    __syncthreads();
    int node = (b << 8) + t;
    if (node < n) dout_cnt[node] = hist[t];
}

__global__ void k_invsqrt2(const unsigned* __restrict__ c0, float* __restrict__ i0,
                           const unsigned* __restrict__ c1, float* __restrict__ i1, int n) {
    int i = blockIdx.x * blockDim.x + threadIdx.x;
    if (i < n) {
        i0[i] = 1.0f / sqrtf(fmaxf((float)c0[i], 1.0f));
        i1[i] = 1.0f / sqrtf(fmaxf((float)c1[i], 1.0f));
    }
}

// ---------------- layer 1 (aggregate-first, 4-wide) ----------------

__global__ void k_prescale4(const float* __restrict__ x, const float* __restrict__ dout_is,
                            float* __restrict__ pf4, int n) {
    int i = blockIdx.x * blockDim.x + threadIdx.x;
    if (i >= n) return;
    float s = dout_is[i];
    float4 v = *reinterpret_cast<const float4*>(x + (size_t)i * 4);
    float4 o = {v.x * s, v.y * s, v.z * s, v.w * s};
    *reinterpret_cast<float4*>(pf4 + (size_t)i * 4) = o;
}

__global__ void k_gather4(const float* __restrict__ pf4, const int* __restrict__ csr,
                          const unsigned* __restrict__ row_ptr, const float* __restrict__ din_is,
                          const float* __restrict__ dout_is, float* __restrict__ a4, int n) {
    int i = blockIdx.x * blockDim.x + threadIdx.x;
    if (i >= n) return;
    unsigned beg = row_ptr[i], end = row_ptr[i + 1];
    float4 acc = {0.f, 0.f, 0.f, 0.f};
    unsigned e = beg;
    for (; e + 4 <= end; e += 4) {
        int s0 = csr[e], s1 = csr[e + 1], s2 = csr[e + 2], s3 = csr[e + 3];
        float4 v0 = *reinterpret_cast<const float4*>(pf4 + (size_t)s0 * 4);
        float4 v1 = *reinterpret_cast<const float4*>(pf4 + (size_t)s1 * 4);
        float4 v2 = *reinterpret_cast<const float4*>(pf4 + (size_t)s2 * 4);
        float4 v3 = *reinterpret_cast<const float4*>(pf4 + (size_t)s3 * 4);
        acc.x += (v0.x + v1.x) + (v2.x + v3.x);
        acc.y += (v0.y + v1.y) + (v2.y + v3.y);
        acc.z += (v0.z + v1.z) + (v2.z + v3.z);
        acc.w += (v0.w + v1.w) + (v2.w + v3.w);
    }
    for (; e < end; ++e) {
        int s = csr[e];
        float4 v = *reinterpret_cast<const float4*>(pf4 + (size_t)s * 4);
        acc.x += v.x; acc.y += v.y; acc.z += v.z; acc.w += v.w;
    }
    float sc = din_is[i] * dout_is[i];
    float4 o = {acc.x * sc, acc.y * sc, acc.z * sc, acc.w * sc};
    *reinterpret_cast<float4*>(a4 + (size_t)i * 4) = o;
}

// ---------------- fp16 helpers ----------------

__device__ inline void sth16(__half* p, const float* v) {
    __half2 hh[8];
#pragma unroll
    for (int q = 0; q < 8; ++q) hh[q] = __floats2half2_rn(v[2 * q], v[2 * q + 1]);
    const float4* f = reinterpret_cast<const float4*>(&hh[0]);
    *reinterpret_cast<float4*>(p) = f[0];
    *reinterpret_cast<float4*>(p + 8) = f[1];
}

// accumulate 8 halves (16B) into acc[8]
__device__ inline void acc8(float* acc, uint4 u) {
    const __half2* h = reinterpret_cast<const __half2*>(&u);
#pragma unroll
    for (int q = 0; q < 4; ++q) {
        float2 f = __half22float2(h[q]);
        acc[2 * q] += f.x;
        acc[2 * q + 1] += f.y;
    }
}

// ---------------- fused layers 1+2 (fp16 out) ----------------

__device__ inline float4 xp1_cols(float4 av, float ds, float4 wa, float4 wb, float4 wc, float4 wd, float4 bc) {
    float4 r;
    r.x = fmaf(av.x, wa.x, fmaf(av.y, wb.x, fmaf(av.z, wc.x, fmaf(av.w, wd.x, ds * bc.x))));
    r.y = fmaf(av.x, wa.y, fmaf(av.y, wb.y, fmaf(av.z, wc.y, fmaf(av.w, wd.y, ds * bc.y))));
    r.z = fmaf(av.x, wa.z, fmaf(av.y, wb.z, fmaf(av.z, wc.z, fmaf(av.w, wd.z, ds * bc.z))));
    r.w = fmaf(av.x, wa.w, fmaf(av.y, wb.w, fmaf(av.z, wc.w, fmaf(av.w, wd.w, ds * bc.w))));
    r.x = (r.x >= 0.f) ? r.x : LRELU_SLOPE * r.x;
    r.y = (r.y >= 0.f) ? r.y : LRELU_SLOPE * r.y;
    r.z = (r.z >= 0.f) ? r.z : LRELU_SLOPE * r.z;
    r.w = (r.w >= 0.f) ? r.w : LRELU_SLOPE * r.w;
    return r;
}

__global__ __launch_bounds__(512) void k_gl12(const float* __restrict__ a4,
                                              const float* __restrict__ dout_v,
                                              const int* __restrict__ csr,
                                              const unsigned* __restrict__ row_ptr,
                                              const float* __restrict__ din_is, const float* __restrict__ dout_is,
                                              const float* __restrict__ W1, const float* __restrict__ b1,
                                              const float* __restrict__ W2, const float* __restrict__ b2,
                                              __half* __restrict__ xh_out, int n) {
    __shared__ float xs[64 * XPAD];  // 33 KB
    const int t = threadIdx.x;
    const int bbase = blockIdx.x * 64;
    const int wave = t >> 6;
    const int lane = t & 63;
    const int half = lane >> 5;
    const int j4 = (lane & 31) * 4;

    float4 wa = *reinterpret_cast<const float4*>(W1 + 0 * 128 + j4);
    float4 wb = *reinterpret_cast<const float4*>(W1 + 1 * 128 + j4);
    float4 wc = *reinterpret_cast<const float4*>(W1 + 2 * 128 + j4);
    float4 wd = *reinterpret_cast<const float4*>(W1 + 3 * 128 + j4);
    float4 bc = *reinterpret_cast<const float4*>(b1 + j4);

#pragma unroll
    for (int sweep = 0; sweep < 4; ++sweep) {
        int r = wave * 2 + half + sweep * 16;
        int node = bbase + r;
        float4 acc = {0.f, 0.f, 0.f, 0.f};
        if (node < n) {
            unsigned beg = row_ptr[node], end = row_ptr[node + 1];
            unsigned e = beg;
            for (; e + 4 <= end; e += 4) {
                int s0 = csr[e + 0], s1 = csr[e + 1], s2 = csr[e + 2], s3 = csr[e + 3];
                float4 a0 = *reinterpret_cast<const float4*>(a4 + (size_t)s0 * 4);
                float4 a1 = *reinterpret_cast<const float4*>(a4 + (size_t)s1 * 4);
                float4 a2 = *reinterpret_cast<const float4*>(a4 + (size_t)s2 * 4);
                float4 a3 = *reinterpret_cast<const float4*>(a4 + (size_t)s3 * 4);
                float d0 = dout_v[s0], d1 = dout_v[s1], d2 = dout_v[s2], d3 = dout_v[s3];
                float4 x0 = xp1_cols(a0, d0, wa, wb, wc, wd, bc);
                float4 x1 = xp1_cols(a1, d1, wa, wb, wc, wd, bc);
                float4 x2 = xp1_cols(a2, d2, wa, wb, wc, wd, bc);
                float4 x3 = xp1_cols(a3, d3, wa, wb, wc, wd, bc);
                acc.x += (x0.x + x1.x) + (x2.x + x3.x);
                acc.y += (x0.y + x1.y) + (x2.y + x3.y);
                acc.z += (x0.z + x1.z) + (x2.z + x3.z);
                acc.w += (x0.w + x1.w) + (x2.w + x3.w);
            }
            for (; e < end; ++e) {
                int s = csr[e];
                float4 av = *reinterpret_cast<const float4*>(a4 + (size_t)s * 4);
                float4 xv = xp1_cols(av, dout_v[s], wa, wb, wc, wd, bc);
                acc.x += xv.x; acc.y += xv.y; acc.z += xv.z; acc.w += xv.w;
            }
            float di = din_is[node];
            acc.x *= di; acc.y *= di; acc.z *= di; acc.w *= di;
        }
        float* d = xs + r * XPAD + j4;
        d[0] = acc.x; d[1] = acc.y; d[2] = acc.z; d[3] = acc.w;
    }
    __syncthreads();

    const int jg = __builtin_amdgcn_readfirstlane(wave) & 7;
    const int j0 = jg * 16;
    const float* Wj = W2 + j0;
    const float* xrow = xs + lane * XPAD;

    float acc[16];
#pragma unroll
    for (int q = 0; q < 16; ++q) acc[q] = 0.f;

#pragma unroll 2
    for (int k = 0; k < 128; k += 4) {
        float x0 = xrow[k + 0];
        float x1 = xrow[k + 1];
        float x2 = xrow[k + 2];
        float x3 = xrow[k + 3];
        const float* w0 = Wj + (size_t)k * 128;
#pragma unroll
        for (int q = 0; q < 16; ++q) {
            acc[q] += x0 * w0[q] + x1 * w0[128 + q] + x2 * w0[256 + q] + x3 * w0[384 + q];
        }
    }

    int node = bbase + lane;
    if (node < n) {
        float s = dout_is[node];
        float v[16];
#pragma unroll
        for (int q = 0; q < 16; ++q) {
            float u = acc[q] + b2[j0 + q];
            u = (u >= 0.f) ? u : LRELU_SLOPE * u;
            v[q] = u * s;
        }
        sth16(xh_out + (size_t)node * 128 + j0, v);
    }
}

// ---------------- fp16 gather macro (paired-edge dwordx4) ----------------
// lanes: half=lane>>5 (node), sub=(lane>>4)&1 (edge slot), c8=(lane&15)*8.

#define GATHER_FP16_TILE(XH)                                                         \
    for (int sweep = 0; sweep < 4; ++sweep) {                                        \
        int r = wave * 2 + half + sweep * 16;                                        \
        int node = bbase + r;                                                        \
        float acc[8];                                                                \
        _Pragma("unroll") for (int q = 0; q < 8; ++q) acc[q] = 0.f;                  \
        float di = 0.f;                                                              \
        if (node < n) {                                                              \
            unsigned beg = row_ptr[node], end = row_ptr[node + 1];                   \
            unsigned e = beg;                                                        \
            for (; e + 8 <= end; e += 8) {                                           \
                int s0 = csr[e + 0 + sub];                                           \
                int s1 = csr[e + 2 + sub];                                           \
                int s2 = csr[e + 4 + sub];                                           \
                int s3 = csr[e + 6 + sub];                                           \
                uint4 u0 = *reinterpret_cast<const uint4*>(XH + (size_t)s0 * 128 + c8); \
                uint4 u1 = *reinterpret_cast<const uint4*>(XH + (size_t)s1 * 128 + c8); \
                uint4 u2 = *reinterpret_cast<const uint4*>(XH + (size_t)s2 * 128 + c8); \
                uint4 u3 = *reinterpret_cast<const uint4*>(XH + (size_t)s3 * 128 + c8); \
                acc8(acc, u0); acc8(acc, u1); acc8(acc, u2); acc8(acc, u3);          \
            }                                                                        \
            for (; e + 2 <= end; e += 2) {                                           \
                int s = csr[e + sub];                                                \
                acc8(acc, *reinterpret_cast<const uint4*>(XH + (size_t)s * 128 + c8)); \
            }                                                                        \
            if (e < end && sub == 0) {                                               \
                int s = csr[e];                                                      \
                acc8(acc, *reinterpret_cast<const uint4*>(XH + (size_t)s * 128 + c8)); \
            }                                                                        \
            di = din_is[node];                                                       \
        }                                                                            \
        _Pragma("unroll") for (int q = 0; q < 8; ++q)                                \
            acc[q] += __shfl_xor(acc[q], 16, 64);                                    \
        if (sub == 0) {                                                              \
            float* d = xs + r * XPAD + c8;                                           \
            _Pragma("unroll") for (int q = 0; q < 8; ++q) d[q] = acc[q] * di;        \
        }                                                                            \
    }

// ---------------- layer 3: fp16 gather -> GEMM -> fp16 out ----------------

__global__ __launch_bounds__(512) void k_gl128h(const __half* __restrict__ xh, const int* __restrict__ csr,
                                                const unsigned* __restrict__ row_ptr,
                                                const float* __restrict__ din_is, const float* __restrict__ dout_is,
                                                const float* __restrict__ W, const float* __restrict__ b,
                                                __half* __restrict__ xh_out, int n) {
    __shared__ float xs[64 * XPAD];  // 33 KB
    const int t = threadIdx.x;
    const int bbase = blockIdx.x * 64;
    const int wave = t >> 6;
    const int lane = t & 63;
    const int half = lane >> 5;
    const int sub = (lane >> 4) & 1;
    const int c8 = (lane & 15) * 8;

    GATHER_FP16_TILE(xh)
    __syncthreads();

    const int jg = __builtin_amdgcn_readfirstlane(wave) & 7;
    const int j0 = jg * 16;
    const float* Wj = W + j0;
    const float* xrow = xs + lane * XPAD;

    float acc[16];
#pragma unroll
    for (int q = 0; q < 16; ++q) acc[q] = 0.f;

#pragma unroll 2
    for (int k = 0; k < 128; k += 4) {
        float x0 = xrow[k + 0];
        float x1 = xrow[k + 1];
        float x2 = xrow[k + 2];
        float x3 = xrow[k + 3];
        const float* w0 = Wj + (size_t)k * 128;
#pragma unroll
        for (int q = 0; q < 16; ++q) {
            acc[q] += x0 * w0[q] + x1 * w0[128 + q] + x2 * w0[256 + q] + x3 * w0[384 + q];
        }
    }

    int node = bbase + lane;
    if (node < n) {
        float s = dout_is[node];
        float v[16];
#pragma unroll
        for (int q = 0; q < 16; ++q) {
            float u = acc[q] + b[j0 + q];
            u = (u >= 0.f) ? u : LRELU_SLOPE * u;
            v[q] = u * s;
        }
        sth16(xh_out + (size_t)node * 128 + j0, v);
    }
}

// ------- layer 4+5 fused: fp16 gather -> GEMM(W4) -> @W5 -> h5 -------

__global__ __launch_bounds__(512) void k_gl128f(const __half* __restrict__ xh, const int* __restrict__ csr,
                                                const unsigned* __restrict__ row_ptr,
                                                const float* __restrict__ din_is, const float* __restrict__ dout_is,
                                                const float* __restrict__ W, const float* __restrict__ b,
                                                const float* __restrict__ W5,
                                                float* __restrict__ h5, int n) {
    __shared__ float xs[64 * XPAD];  // 33 KB (reused for the L5 reduction)
    const int t = threadIdx.x;
    const int bbase = blockIdx.x * 64;
    const int wave = t >> 6;
    const int lane = t & 63;
    const int half = lane >> 5;
    const int sub = (lane >> 4) & 1;
    const int c8 = (lane & 15) * 8;

    GATHER_FP16_TILE(xh)
    __syncthreads();

    const int jg = __builtin_amdgcn_readfirstlane(wave) & 7;
    const int j0 = jg * 16;
    const float* Wj = W + j0;
    const float* xrow = xs + lane * XPAD;

    float acc[16];
#pragma unroll
    for (int q = 0; q < 16; ++q) acc[q] = 0.f;

#pragma unroll 2
    for (int k = 0; k < 128; k += 4) {
        float x0 = xrow[k + 0];
        float x1 = xrow[k + 1];
        float x2 = xrow[k + 2];
        float x3 = xrow[k + 3];
        const float* w0 = Wj + (size_t)k * 128;
#pragma unroll
        for (int q = 0; q < 16; ++q) {
            acc[q] += x0 * w0[q] + x1 * w0[128 + q] + x2 * w0[256 + q] + x3 * w0[384 + q];
        }
    }

    // epilogue: xp4 cols -> partial (xp4 @ W5) 3-vector per (node, wave)
    float s = (bbase + lane < n) ? dout_is[bbase + lane] : 0.f;
    float p0 = 0.f, p1 = 0.f, p2 = 0.f;
#pragma unroll
    for (int q = 0; q < 16; ++q) {
        float u = acc[q] + b[j0 + q];
        u = (u >= 0.f) ? u : LRELU_SLOPE * u;
        u *= s;
        const float* w5r = W5 + (size_t)(j0 + q) * 3;
        p0 = fmaf(u, w5r[0], p0);
        p1 = fmaf(u, w5r[1], p1);
        p2 = fmaf(u, w5r[2], p2);
    }
    __syncthreads();  // xs reads done; reuse as reduction scratch
    float* red = xs;  // layout: [node(64)][wave(8)][3]
    red[lane * 24 + wave * 3 + 0] = p0;
    red[lane * 24 + wave * 3 + 1] = p1;
    red[lane * 24 + wave * 3 + 2] = p2;
    __syncthreads();
    if (t < 64) {
        int node = bbase + t;
        if (node < n) {
            float a0 = 0.f, a1 = 0.f, a2 = 0.f;
#pragma unroll
            for (int w = 0; w < 8; ++w) {
                a0 += red[t * 24 + w * 3 + 0];
                a1 += red[t * 24 + w * 3 + 1];
                a2 += red[t * 24 + w * 3 + 2];
            }
            h5[(size_t)node * 3 + 0] = a0;
            h5[(size_t)node * 3 + 1] = a1;
            h5[(size_t)node * 3 + 2] = a2;
        }
    }
}

// ---------------- final 3-wide gather ----------------

__global__ void k_gather3(const float* __restrict__ h, const int* __restrict__ csr,
                          const unsigned* __restrict__ row_ptr, const float* __restrict__ din_is,
                          const float* __restrict__ b, float* __restrict__ out, int n) {
    int i = blockIdx.x * blockDim.x + threadIdx.x;
    if (i >= n) return;
    unsigned beg = row_ptr[i], end = row_ptr[i + 1];
    float a0 = 0.f, a1 = 0.f, a2 = 0.f;
    for (unsigned e = beg; e < end; ++e) {
        int s = csr[e];
        a0 += h[(size_t)s * 3 + 0];
        a1 += h[(size_t)s * 3 + 1];
        a2 += h[(size_t)s * 3 + 2];
    }
    float di = din_is[i];
    out[(size_t)i * 3 + 0] = a0 * di + b[0];
    out[(size_t)i * 3 + 1] = a1 * di + b[1];
    out[(size_t)i * 3 + 2] = a2 * di + b[2];
}

// ---------------- launch ----------------

extern "C" void kernel_launch(void* const* d_in, const int* in_sizes, int n_in,
                              void* d_out, int out_size, void* d_ws, size_t ws_size,
                              hipStream_t stream) {
    const float* features = (const float*)d_in[0];
    const int* esrc = (const int*)d_in[1];
    const int* edst = (const int*)d_in[2];
    const float* W1 = (const float*)d_in[3];  const float* b1 = (const float*)d_in[4];
    const float* W2 = (const float*)d_in[5];  const float* b2 = (const float*)d_in[6];
    const float* W3 = (const float*)d_in[7];  const float* b3 = (const float*)d_in[8];
    const float* W4 = (const float*)d_in[9];  const float* b4 = (const float*)d_in[10];
    const float* W5 = (const float*)d_in[11]; const float* b5 = (const float*)d_in[12];

    const int N = in_sizes[0] / 4;
    const int E = in_sizes[1];
    const int nbuck = (N + 255) / 256;
    const int NPB = 256;

    size_t off = 0;
    auto carve = [&](size_t bytes) -> void* {
        void* p = (char*)d_ws + off;
        off = (off + bytes + 255) & ~(size_t)255;
        return p;
    };
    char*     scratch   = (char*)carve((size_t)E * 12 + 256);   // pairs + srcbuf
    float*    Bp        = (float*)carve((size_t)N * 8 * 4);     // pf4 + a4
    __half*   xh2       = (__half*)carve((size_t)N * 128 * 2);
    __half*   xh3       = (__half*)carve((size_t)N * 128 * 2);
    int*      csr       = (int*)carve((size_t)E * 4);
    unsigned* row_ptr   = (unsigned*)carve((size_t)(N + 1) * 4);
    unsigned* dout_cnt  = (unsigned*)carve((size_t)N * 4);
    unsigned* din_cnt   = (unsigned*)carve((size_t)N * 4);
    float*    dout_is   = (float*)carve((size_t)N * 4);
    float*    din_is    = (float*)carve((size_t)N * 4);
    unsigned* gHistD    = (unsigned*)carve((size_t)MAXBUCK * 4);
    unsigned* gHistS    = (unsigned*)carve((size_t)MAXBUCK * 4);
    unsigned* bstartD   = (unsigned*)carve((size_t)(MAXBUCK + 1) * 4);
    unsigned* bstartS   = (unsigned*)carve((size_t)(MAXBUCK + 1) * 4);
    unsigned* blockBaseD = (unsigned*)carve((size_t)NPB * nbuck * 4);
    unsigned* blockBaseS = (unsigned*)carve((size_t)NPB * nbuck * 4);
    float*    h5        = (float*)carve((size_t)N * 3 * 4);
    (void)ws_size;
    int2* pairs  = (int2*)scratch;
    int*  srcbuf = (int*)(scratch + (size_t)E * 8);
    float* pf4 = Bp;
    float* a4  = Bp + (size_t)N * 4;

    hipMemsetAsync(gHistD, 0, (size_t)MAXBUCK * 4, stream);
    hipMemsetAsync(gHistS, 0, (size_t)MAXBUCK * 4, stream);

    // ---- bucket-partition preprocessing ----
    k_part_hist2<<<NPB, 256, 0, stream>>>(esrc, edst, E, nbuck, gHistS, gHistD, blockBaseS, blockBaseD);
    k_part_scan<<<1, 512, 0, stream>>>(gHistD, nbuck, bstartD, row_ptr + N, (unsigned)E);
    k_part_scan<<<1, 512, 0, stream>>>(gHistS, nbuck, bstartS, (unsigned*)nullptr, 0u);
    k_part_scatter_both<<<NPB, 256, 0, stream>>>(esrc, edst, E, nbuck, bstartS, bstartD,
                                                 blockBaseS, blockBaseD, pairs, srcbuf);
    k_bucket_csr<<<nbuck, 256, 0, stream>>>(pairs, bstartD, row_ptr, din_cnt, csr, N);
    k_bucket_cnt<<<nbuck, 256, 0, stream>>>(srcbuf, bstartS, dout_cnt, N);
    k_invsqrt2<<<(N + 255) / 256, 256, 0, stream>>>(dout_cnt, dout_is, din_cnt, din_is, N);

    // ---- layer 1 prep: 4-wide prescale + aggregate ----
    k_prescale4<<<(N + 255) / 256, 256, 0, stream>>>(features, dout_is, pf4, N);
    k_gather4<<<(N + 255) / 256, 256, 0, stream>>>(pf4, csr, row_ptr, din_is, dout_is, a4, N);

    // ---- layers 1+2 fused -> fp16; L3 fp16; L4+L5 fused -> h5 ----
    int glGrid = (N + 63) / 64;
    k_gl12<<<glGrid, 512, 0, stream>>>(a4, dout_is, csr, row_ptr, din_is, dout_is, W1, b1, W2, b2, xh2, N);
    k_gl128h<<<glGrid, 512, 0, stream>>>(xh2, csr, row_ptr, din_is, dout_is, W3, b3, xh3, N);
    k_gl128f<<<glGrid, 512, 0, stream>>>(xh3, csr, row_ptr, din_is, dout_is, W4, b4, W5, h5, N);

    // ---- final gather ----
    k_gather3<<<(N + 255) / 256, 256, 0, stream>>>(h5, csr, row_ptr, din_is, b5, (float*)d_out, N);
}